// Round 8
// baseline (70.005 us; speedup 1.0000x reference)
//
#include <hip/hip_runtime.h>
#include <math.h>

#define SQ 768
#define DMODEL 256
#define NH 8
#define DHD 32
#define NB 12                       // query blocks (SQ/64)
#define QSCALE 0.1767766952966369f  // 32^-0.5
#define PSHIFT 8.0f                 // fixed softmax shift (math-equiv to max-sub)

// ---------------------------------------------------------------------------
// Ledger (R5 double-launch + R7): F=5.8us, attn2_v3=23.2us, proj3_v6=20.0us.
// proj3 anomaly: 4 variants x 3 theories all land 20-30us vs 5-7us models;
// warm (pass-2) proj3 still >=17us; R1's v2 = 43us ~= the 256MB fill's 42us.
// THEORY UNDER TEST: first kernel runs in the fill's writeback/flush shadow
// (HBM saturated, L2 churning) -> dependent cold reads see multi-x latency.
// warmup = throughput-mode streamer that absorbs the shadow with pure MLP:
// blocks 0..63 stream all W (every XCD L2 gets W); blocks 64..319 grid-stride
// X/aidx/mask. No dependent chains -> degrades gracefully under contention.
// ---------------------------------------------------------------------------
__global__ __launch_bounds__(256) void warmup(
    const float4* __restrict__ q4, const float4* __restrict__ v4,
    const float4* __restrict__ k4, const float4* __restrict__ wq4,
    const float4* __restrict__ wk4, const float4* __restrict__ wv4,
    const float4* __restrict__ a4, const float4* __restrict__ m4,
    float* __restrict__ sink)
{
    const int bid = blockIdx.x, tid = threadIdx.x;
    float acc = 0.f;
    if (bid < 64) {
        // stream Wq,Wk,Wv fully: 16384 float4 each, stride-256 (coalesced)
        for (int i = tid; i < 16384; i += 256) {
            float4 a = wq4[i], b = wk4[i], c = wv4[i];
            acc += a.x + a.y + a.z + a.w;
            acc += b.x + b.y + b.z + b.w;
            acc += c.x + c.y + c.z + c.w;
        }
    } else {
        const int g = (bid - 64) * 256 + tid;          // 0..65535
        if (g < 49152) {                               // X arrays: 49152 f4 each
            float4 a = q4[g], b = v4[g], c = k4[g];
            acc += a.x + a.y + a.z + a.w;
            acc += b.x + b.y + b.z + b.w;
            acc += c.x + c.y + c.z + c.w;
        }
        for (int i = g; i < 147456; i += 65536) {      // aidx + mask: 147456 f4
            float4 a = a4[i], b = m4[i];
            acc += a.x + a.y + a.z + a.w;
            acc += b.x + b.y + b.z + b.w;
        }
    }
    // keep loads live; condition is (effectively) never true, and the target
    // (vhp scratch) is fully overwritten by proj3 before any consumer.
    if (acc == 123456789.0f) sink[0] = acc;
}

// ---------------------------------------------------------------------------
// Node 1 (v6, byte-identical to R7): W staged through LDS in 8 double-
// buffered 32-k chunks, reg-staged async-split. 8 rows/block, grid (96,3).
// ---------------------------------------------------------------------------
__global__ __launch_bounds__(256) void proj3(
    const float* __restrict__ query, const float* __restrict__ value,
    const float* __restrict__ key_in,
    const float* __restrict__ Wq, const float* __restrict__ bq,
    const float* __restrict__ Wk, const float* __restrict__ bk,
    const float* __restrict__ Wv, const float* __restrict__ bv,
    const float* __restrict__ bo, float* __restrict__ outbuf,
    const int* __restrict__ aidx, float* __restrict__ idx_out,
    float* __restrict__ qhp, float* __restrict__ khp, float* __restrict__ vhp)
{
    const int j = threadIdx.x;

    // idx -> float copy: 288 blocks * 256 threads * 8 elems == 589824 exactly
    {
        const int bidf = blockIdx.y * 96 + blockIdx.x;
        const int i0 = (bidf * 256 + j) * 8;
        int4 a = *(const int4*)&aidx[i0];
        int4 b = *(const int4*)&aidx[i0 + 4];
        *(float4*)&idx_out[i0] =
            make_float4((float)a.x, (float)a.y, (float)a.z, (float)a.w);
        *(float4*)&idx_out[i0 + 4] =
            make_float4((float)b.x, (float)b.y, (float)b.z, (float)b.w);
    }

    const int s0 = blockIdx.x * 8;
    const int w  = blockIdx.y;

    if (w == 0) {   // init out rows with bias (node-2 atomically accumulates)
        const float bb = bo[j];
        #pragma unroll
        for (int r = 0; r < 8; ++r)
            outbuf[(s0 + r) * DMODEL + j] = bb;
    }

    const float *X, *W, *bias; float* outp; float scale;
    if (w == 0)      { X = query;  W = Wq; bias = bq; outp = qhp; scale = QSCALE; }
    else if (w == 1) { X = key_in; W = Wk; bias = bk; outp = khp; scale = 1.0f; }
    else             { X = value;  W = Wv; bias = bv; outp = vhp; scale = 1.0f; }

    __shared__ __align__(16) float xs[8][DMODEL];     // 8KB
    __shared__ __align__(16) float ws[2][32 * DMODEL]; // 64KB (dbuf, 32k x 256c)

    // stage X (8 rows) + W chunk 0, then barrier
    {
        float* xsf = &xs[0][0];
        const float* Xp = X + s0 * DMODEL;
        const int i0 = j * 8;
        *(float4*)&xsf[i0]     = *(const float4*)&Xp[i0];
        *(float4*)&xsf[i0 + 4] = *(const float4*)&Xp[i0 + 4];

        #pragma unroll
        for (int t = 0; t < 8; ++t)
            *(float4*)&ws[0][t * 1024 + j * 4] =
                *(const float4*)&W[t * 1024 + j * 4];
    }
    __syncthreads();

    const int j0 = (j & 63) * 4;        // 4 consecutive output cols
    const int r0 = (j >> 6) * 2;        // 2 rows (wave-uniform -> broadcast)

    float4 acc0 = make_float4(0.f, 0.f, 0.f, 0.f);
    float4 acc1 = make_float4(0.f, 0.f, 0.f, 0.f);
    int cur = 0;

    for (int c = 0; c < 8; ++c) {
        // issue next chunk's global loads early (hide latency under FMA)
        float4 wreg[8];
        if (c < 7) {
            const float* Wc = W + (c + 1) * 8192;
            #pragma unroll
            for (int t = 0; t < 8; ++t)
                wreg[t] = *(const float4*)&Wc[t * 1024 + j * 4];
        }

        // compute chunk c from LDS
        const float* wb = &ws[cur][0];
        #pragma unroll
        for (int k4 = 0; k4 < 8; ++k4) {
            const int kb = c * 32 + k4 * 4;
            float4 x0 = *(const float4*)&xs[r0 + 0][kb];
            float4 x1 = *(const float4*)&xs[r0 + 1][kb];
            float4 w0 = *(const float4*)&wb[(k4 * 4 + 0) * DMODEL + j0];
            float4 w1 = *(const float4*)&wb[(k4 * 4 + 1) * DMODEL + j0];
            float4 w2 = *(const float4*)&wb[(k4 * 4 + 2) * DMODEL + j0];
            float4 w3 = *(const float4*)&wb[(k4 * 4 + 3) * DMODEL + j0];
            acc0.x = fmaf(x0.x, w0.x, acc0.x); acc0.y = fmaf(x0.x, w0.y, acc0.y);
            acc0.z = fmaf(x0.x, w0.z, acc0.z); acc0.w = fmaf(x0.x, w0.w, acc0.w);
            acc0.x = fmaf(x0.y, w1.x, acc0.x); acc0.y = fmaf(x0.y, w1.y, acc0.y);
            acc0.z = fmaf(x0.y, w1.z, acc0.z); acc0.w = fmaf(x0.y, w1.w, acc0.w);
            acc0.x = fmaf(x0.z, w2.x, acc0.x); acc0.y = fmaf(x0.z, w2.y, acc0.y);
            acc0.z = fmaf(x0.z, w2.z, acc0.z); acc0.w = fmaf(x0.z, w2.w, acc0.w);
            acc0.x = fmaf(x0.w, w3.x, acc0.x); acc0.y = fmaf(x0.w, w3.y, acc0.y);
            acc0.z = fmaf(x0.w, w3.z, acc0.z); acc0.w = fmaf(x0.w, w3.w, acc0.w);
            acc1.x = fmaf(x1.x, w0.x, acc1.x); acc1.y = fmaf(x1.x, w0.y, acc1.y);
            acc1.z = fmaf(x1.x, w0.z, acc1.z); acc1.w = fmaf(x1.x, w0.w, acc1.w);
            acc1.x = fmaf(x1.y, w1.x, acc1.x); acc1.y = fmaf(x1.y, w1.y, acc1.y);
            acc1.z = fmaf(x1.y, w1.z, acc1.z); acc1.w = fmaf(x1.y, w1.w, acc1.w);
            acc1.x = fmaf(x1.z, w2.x, acc1.x); acc1.y = fmaf(x1.z, w2.y, acc1.y);
            acc1.z = fmaf(x1.z, w2.z, acc1.z); acc1.w = fmaf(x1.z, w2.w, acc1.w);
            acc1.x = fmaf(x1.w, w3.x, acc1.x); acc1.y = fmaf(x1.w, w3.y, acc1.y);
            acc1.z = fmaf(x1.w, w3.z, acc1.z); acc1.w = fmaf(x1.w, w3.w, acc1.w);
        }

        if (c < 7) {
            float* wd = &ws[cur ^ 1][0];
            #pragma unroll
            for (int t = 0; t < 8; ++t)
                *(float4*)&wd[t * 1024 + j * 4] = wreg[t];
            __syncthreads();
            cur ^= 1;
        }
    }

    const float4 bb = *(const float4*)&bias[j0];
    const int h = j0 >> 5, d = j0 & 31;
    {
        float4 o0, o1;
        o0.x = (acc0.x + bb.x) * scale; o0.y = (acc0.y + bb.y) * scale;
        o0.z = (acc0.z + bb.z) * scale; o0.w = (acc0.w + bb.w) * scale;
        o1.x = (acc1.x + bb.x) * scale; o1.y = (acc1.y + bb.y) * scale;
        o1.z = (acc1.z + bb.z) * scale; o1.w = (acc1.w + bb.w) * scale;
        *(float4*)&outp[h * (SQ * DHD) + (s0 + r0 + 0) * DHD + d] = o0;
        *(float4*)&outp[h * (SQ * DHD) + (s0 + r0 + 1) * DHD + d] = o1;
    }
}

// ---------------------------------------------------------------------------
// Node 2 (v3, byte-identical to R6/R7, measured 23.2us).
// ---------------------------------------------------------------------------
__global__ __launch_bounds__(512) void attn2(
    const float* __restrict__ qh, const float* __restrict__ kh,
    const float* __restrict__ vh, const int* __restrict__ aidx,
    const float* __restrict__ mask, const float* __restrict__ Wo,
    float* __restrict__ scores_out, float* __restrict__ out, int M)
{
    __shared__ __align__(16) float Ks[2][2][32][68];   // [unit][buf][d][c]
    __shared__ __align__(16) float Vs[2][2][64][36];   // [unit][buf][c][d]
    __shared__ __align__(16) float Ps[2][32][68];      // [unit][row][c]
    __shared__ float dot0s[32];
    __shared__ float invL[32];

    const int b    = blockIdx.x;
    const int half = blockIdx.y;
    const int h    = blockIdx.z;
    const int s0b  = b * 64;
    const int s0   = s0b + half * 32;
    const int tid  = threadIdx.x;
    const int u    = tid >> 8;        // unit 0/1
    const int utid = tid & 255;
    const int NCH2 = M / 128;         // chunks per unit

    const int qrt = (utid & 15) * 2;  // QK rows (2)
    const int qct = (utid >> 4) * 4;  // QK cols (4)
    const int rp  = utid & 15;            // row pair
    const int dg  = (utid >> 4) & 3;      // dim group (8 dims)
    const int cg  = utid >> 6;            // c group (16 c's)
    const int c   = utid & 63;        // staging token within chunk
    const int sg  = utid >> 6;        // staging dim group 0..3
    const int d4a = sg * 4;
    const int d4b = 16 + sg * 4;

    const float* mrow = &mask[s0b * M];
    const int*   arow = &aidx[s0b * M];
    float*       srow = &scores_out[(h * SQ + s0) * M];

    // ---- Q rows (qrt, qrt+1) fully in registers ----
    float qr0[32], qr1[32];
    {
        const float* qp = &qh[(h * SQ + s0 + qrt) * DHD];
        #pragma unroll
        for (int d4 = 0; d4 < DHD; d4 += 4) {
            float4 a  = *(const float4*)&qp[d4];
            float4 b4 = *(const float4*)&qp[DHD + d4];
            qr0[d4] = a.x;  qr0[d4+1] = a.y;  qr0[d4+2] = a.z;  qr0[d4+3] = a.w;
            qr1[d4] = b4.x; qr1[d4+1] = b4.y; qr1[d4+2] = b4.z; qr1[d4+3] = b4.w;
        }
    }

    // dot0[r] = q_row . k[token 0]  (chunk-invariant; for padded chunks)
    if (tid < 16) {
        const float* k0 = &kh[h * SQ * DHD];
        float a0 = 0.f, a1 = 0.f;
        #pragma unroll
        for (int d = 0; d < DHD; ++d) {
            const float kv = k0[d];
            a0 = fmaf(qr0[d], kv, a0);
            a1 = fmaf(qr1[d], kv, a1);
        }
        dot0s[qrt] = a0; dot0s[qrt + 1] = a1;
    }

    // ---- prologue: stage this unit's chunk 0 into buffer 0 ----
    float mv_cur = mrow[(u * NCH2) * 64];
    bool  val_cur = mv_cur > -0.5f;
    if (val_cur) {
        const int t0 = arow[(u * NCH2) * 64];
        const float* kp = &kh[(h * SQ + t0 + c) * DHD];
        const float* vp = &vh[(h * SQ + t0 + c) * DHD];
        float4 ka = *(const float4*)&kp[d4a];
        float4 kb = *(const float4*)&kp[d4b];
        Ks[u][0][d4a+0][c] = ka.x; Ks[u][0][d4a+1][c] = ka.y;
        Ks[u][0][d4a+2][c] = ka.z; Ks[u][0][d4a+3][c] = ka.w;
        Ks[u][0][d4b+0][c] = kb.x; Ks[u][0][d4b+1][c] = kb.y;
        Ks[u][0][d4b+2][c] = kb.z; Ks[u][0][d4b+3][c] = kb.w;
        *(float4*)&Vs[u][0][c][d4a] = *(const float4*)&vp[d4a];
        *(float4*)&Vs[u][0][c][d4b] = *(const float4*)&vp[d4b];
    }
    __syncthreads();

    float4 acc0a = make_float4(0.f,0.f,0.f,0.f), acc0b = acc0a;
    float4 acc1a = acc0a, acc1b = acc0a;
    float rps0 = 0.f, rps1 = 0.f;
    int cur = 0;

    for (int ci = 0; ci < NCH2; ++ci) {
        const int m0 = (u * NCH2 + ci) * 64;

        bool  val_nxt = false;
        float mv_nxt  = 0.f;
        float4 ka, kb, va, vb;
        if (ci + 1 < NCH2) {
            mv_nxt  = mrow[m0 + 64];
            val_nxt = mv_nxt > -0.5f;
            if (val_nxt) {
                const int t0 = arow[m0 + 64];
                const float* kp = &kh[(h * SQ + t0 + c) * DHD];
                const float* vp = &vh[(h * SQ + t0 + c) * DHD];
                ka = *(const float4*)&kp[d4a];
                kb = *(const float4*)&kp[d4b];
                va = *(const float4*)&vp[d4a];
                vb = *(const float4*)&vp[d4b];
            }
        }

        if (val_cur) {
            const float* Kb = &Ks[u][cur][0][qct];
            float sc[2][4] = {};
            #pragma unroll
            for (int kk = 0; kk < 32; ++kk) {
                float4 b4 = *(const float4*)&Kb[kk * 68];
                sc[0][0] = fmaf(qr0[kk], b4.x, sc[0][0]);
                sc[0][1] = fmaf(qr0[kk], b4.y, sc[0][1]);
                sc[0][2] = fmaf(qr0[kk], b4.z, sc[0][2]);
                sc[0][3] = fmaf(qr0[kk], b4.w, sc[0][3]);
                sc[1][0] = fmaf(qr1[kk], b4.x, sc[1][0]);
                sc[1][1] = fmaf(qr1[kk], b4.y, sc[1][1]);
                sc[1][2] = fmaf(qr1[kk], b4.z, sc[1][2]);
                sc[1][3] = fmaf(qr1[kk], b4.w, sc[1][3]);
            }
            {
                *(float4*)&srow[(qrt + 0) * M + m0 + qct] =
                    make_float4(sc[0][0], sc[0][1], sc[0][2], sc[0][3]);
                float4 e;
                e.x = __expf(sc[0][0] - PSHIFT); e.y = __expf(sc[0][1] - PSHIFT);
                e.z = __expf(sc[0][2] - PSHIFT); e.w = __expf(sc[0][3] - PSHIFT);
                *(float4*)&Ps[u][qrt + 0][qct] = e;
                rps0 += (e.x + e.y) + (e.z + e.w);
            }
            {
                *(float4*)&srow[(qrt + 1) * M + m0 + qct] =
                    make_float4(sc[1][0], sc[1][1], sc[1][2], sc[1][3]);
                float4 e;
                e.x = __expf(sc[1][0] - PSHIFT); e.y = __expf(sc[1][1] - PSHIFT);
                e.z = __expf(sc[1][2] - PSHIFT); e.w = __expf(sc[1][3] - PSHIFT);
                *(float4*)&Ps[u][qrt + 1][qct] = e;
                rps1 += (e.x + e.y) + (e.z + e.w);
            }
        } else {
            #pragma unroll
            for (int i = 0; i < 8; ++i) {
                const int e = utid + i * 256;
                const int r = e >> 6, cc = e & 63;
                srow[r * M + m0 + cc] = dot0s[r] + mv_cur;
            }
        }

        if (val_nxt) {
            Ks[u][cur^1][d4a+0][c] = ka.x; Ks[u][cur^1][d4a+1][c] = ka.y;
            Ks[u][cur^1][d4a+2][c] = ka.z; Ks[u][cur^1][d4a+3][c] = ka.w;
            Ks[u][cur^1][d4b+0][c] = kb.x; Ks[u][cur^1][d4b+1][c] = kb.y;
            Ks[u][cur^1][d4b+2][c] = kb.z; Ks[u][cur^1][d4b+3][c] = kb.w;
            *(float4*)&Vs[u][cur^1][c][d4a] = va;
            *(float4*)&Vs[u][cur^1][c][d4b] = vb;
        }
        __syncthreads();

        if (val_cur) {
            const float (*Vb)[36] = Vs[u][cur];
            const float* Pr0 = &Ps[u][2 * rp][0];
            const float* Pr1 = &Ps[u][2 * rp + 1][0];
            const int c0 = cg * 16;
            const int dd = dg * 8;
            #pragma unroll
            for (int k = 0; k < 4; ++k) {
                float4 pa = *(const float4*)&Pr0[c0 + k * 4];
                float4 pb = *(const float4*)&Pr1[c0 + k * 4];
                const float pav[4] = {pa.x, pa.y, pa.z, pa.w};
                const float pbv[4] = {pb.x, pb.y, pb.z, pb.w};
                #pragma unroll
                for (int t = 0; t < 4; ++t) {
                    const int cc2 = c0 + k * 4 + t;
                    float4 v0 = *(const float4*)&Vb[cc2][dd];
                    float4 v1 = *(const float4*)&Vb[cc2][dd + 4];
                    acc0a.x = fmaf(pav[t], v0.x, acc0a.x);
                    acc0a.y = fmaf(pav[t], v0.y, acc0a.y);
                    acc0a.z = fmaf(pav[t], v0.z, acc0a.z);
                    acc0a.w = fmaf(pav[t], v0.w, acc0a.w);
                    acc0b.x = fmaf(pav[t], v1.x, acc0b.x);
                    acc0b.y = fmaf(pav[t], v1.y, acc0b.y);
                    acc0b.z = fmaf(pav[t], v1.z, acc0b.z);
                    acc0b.w = fmaf(pav[t], v1.w, acc0b.w);
                    acc1a.x = fmaf(pbv[t], v0.x, acc1a.x);
                    acc1a.y = fmaf(pbv[t], v0.y, acc1a.y);
                    acc1a.z = fmaf(pbv[t], v0.z, acc1a.z);
                    acc1a.w = fmaf(pbv[t], v0.w, acc1a.w);
                    acc1b.x = fmaf(pbv[t], v1.x, acc1b.x);
                    acc1b.y = fmaf(pbv[t], v1.y, acc1b.y);
                    acc1b.z = fmaf(pbv[t], v1.z, acc1b.z);
                    acc1b.w = fmaf(pbv[t], v1.w, acc1b.w);
                }
            }
        }
        __syncthreads();

        val_cur = val_nxt; mv_cur = mv_nxt; cur ^= 1;
    }

    // ---- epilogue: reduce 8 slabs + 32 rps slices ----
    float* vacc = &Vs[0][0][0][0];              // vacc[8][32][36] overlay
    float* rsum = &Ps[0][0][0];                 // rsum[32][32] overlay
    {
        const int s = u * 4 + cg;
        float* base = vacc + (s * 32 + 2 * rp) * 36 + dg * 8;
        *(float4*)&base[0]  = acc0a; *(float4*)&base[4]  = acc0b;
        *(float4*)&base[36] = acc1a; *(float4*)&base[40] = acc1b;
        const int qg = utid >> 4;               // 0..15
        rsum[(u * 16 + qg) * 32 + qrt]     = rps0;
        rsum[(u * 16 + qg) * 32 + qrt + 1] = rps1;
    }
    __syncthreads();

    if (tid < 32) {
        float pt = 0.f;
        #pragma unroll
        for (int s2 = 0; s2 < 32; ++s2) pt += rsum[s2 * 32 + tid];
        invL[tid] = 1.0f / pt;
    }
    __syncthreads();

    float* ctxn = &Ks[0][0][0][0];              // ctxn[32][36] overlay
    if (tid < 256) {
        const int r = tid & 31, dq = tid >> 5;  // 8 dim-quads
        float4 sum = make_float4(0.f, 0.f, 0.f, 0.f);
        #pragma unroll
        for (int s = 0; s < 8; ++s) {
            float4 v = *(const float4*)&vacc[(s * 32 + r) * 36 + dq * 4];
            sum.x += v.x; sum.y += v.y; sum.z += v.z; sum.w += v.w;
        }
        const float il = invL[r];
        sum.x *= il; sum.y *= il; sum.z *= il; sum.w *= il;
        *(float4*)&ctxn[r * 36 + dq * 4] = sum;
    }
    __syncthreads();

    // ---- per-head outproj partial, atomically accumulated into out ----
    {
        const int jc = tid & 255, rg = tid >> 8;
        float wo[32];
        #pragma unroll
        for (int k = 0; k < 32; ++k)
            wo[k] = Wo[(h * DHD + k) * DMODEL + jc];
        for (int rr = rg * 16; rr < rg * 16 + 16; ++rr) {
            float a = 0.f;
            #pragma unroll
            for (int k4 = 0; k4 < 8; ++k4) {
                float4 cv = *(const float4*)&ctxn[rr * 36 + k4 * 4];
                a = fmaf(cv.x, wo[k4 * 4 + 0], a);
                a = fmaf(cv.y, wo[k4 * 4 + 1], a);
                a = fmaf(cv.z, wo[k4 * 4 + 2], a);
                a = fmaf(cv.w, wo[k4 * 4 + 3], a);
            }
            atomicAdd(&out[(s0 + rr) * DMODEL + jc], a);
        }
    }
}

extern "C" void kernel_launch(void* const* d_in, const int* in_sizes, int n_in,
                              void* d_out, int out_size, void* d_ws, size_t ws_size,
                              hipStream_t stream)
{
    const float* query  = (const float*)d_in[0];
    const float* value  = (const float*)d_in[1];
    const float* key_in = (const float*)d_in[2];
    const float* Wq = (const float*)d_in[3];
    const float* bq = (const float*)d_in[4];
    const float* Wk = (const float*)d_in[5];
    const float* bk = (const float*)d_in[6];
    const float* Wv = (const float*)d_in[7];
    const float* bv = (const float*)d_in[8];
    const float* Wo = (const float*)d_in[9];
    const float* bo = (const float*)d_in[10];
    const int*   aidx = (const int*)d_in[11];
    const float* mask = (const float*)d_in[12];

    const int M = in_sizes[11] / SQ;   // 768

    float* out        = (float*)d_out;
    float* scores_out = out + SQ * DMODEL;
    float* idx_out    = scores_out + NH * SQ * M;

    float* ws  = (float*)d_ws;
    float* qhp = ws;
    float* khp = qhp + NH * SQ * DHD;
    float* vhp = khp + NH * SQ * DHD;

    // warm-streamer: absorbs the post-fill writeback/flush shadow with pure
    // throughput reads; sink = vhp (fully overwritten by proj3 afterwards).
    warmup<<<dim3(320), 256, 0, stream>>>(
        (const float4*)query, (const float4*)value, (const float4*)key_in,
        (const float4*)Wq, (const float4*)Wk, (const float4*)Wv,
        (const float4*)aidx, (const float4*)mask, vhp);

    proj3<<<dim3(96, 3), 256, 0, stream>>>(
        query, value, key_in, Wq, bq, Wk, bk, Wv, bv,
        bo, out, aidx, idx_out, qhp, khp, vhp);

    attn2<<<dim3(NB, 2, NH), 512, 0, stream>>>(
        qhp, khp, vhp, aidx, mask, Wo, scores_out, out, M);
}

// Round 9
// 60.044 us; speedup vs baseline: 1.1659x; 1.1659x over previous
//
#include <hip/hip_runtime.h>
#include <math.h>

#define SQ 768
#define DMODEL 256
#define NH 8
#define DHD 32
#define NB 12                       // query blocks (SQ/64)
#define QSCALE 0.1767766952966369f  // 32^-0.5
#define PSHIFT 8.0f                 // fixed softmax shift (math-equiv to max-sub)

// ---------------------------------------------------------------------------
// Ledger (validated R5 algebra): F=5.8us, proj3_v6=20.0us, attn2_v3=23.2us.
// R8: warmup streamer +21us, NO proj3 benefit -> post-fill "shadow absorption"
// refuted. Unified theory: both kernels run ~4x slower than issue models
// (attn2 6.2->23.2, proj3 5->20): low effective SCLK during our window +
// per-dispatch L2 invalidation. Only lever: CUT CYCLES.
//
// Node 1 (v6, byte-identical to R7): W staged through LDS, 8 dbuf chunks.
// ---------------------------------------------------------------------------
__global__ __launch_bounds__(256) void proj3(
    const float* __restrict__ query, const float* __restrict__ value,
    const float* __restrict__ key_in,
    const float* __restrict__ Wq, const float* __restrict__ bq,
    const float* __restrict__ Wk, const float* __restrict__ bk,
    const float* __restrict__ Wv, const float* __restrict__ bv,
    const float* __restrict__ bo, float* __restrict__ outbuf,
    const int* __restrict__ aidx, float* __restrict__ idx_out,
    float* __restrict__ qhp, float* __restrict__ khp, float* __restrict__ vhp)
{
    const int j = threadIdx.x;

    // idx -> float copy: 288 blocks * 256 threads * 8 elems == 589824 exactly
    {
        const int bidf = blockIdx.y * 96 + blockIdx.x;
        const int i0 = (bidf * 256 + j) * 8;
        int4 a = *(const int4*)&aidx[i0];
        int4 b = *(const int4*)&aidx[i0 + 4];
        *(float4*)&idx_out[i0] =
            make_float4((float)a.x, (float)a.y, (float)a.z, (float)a.w);
        *(float4*)&idx_out[i0 + 4] =
            make_float4((float)b.x, (float)b.y, (float)b.z, (float)b.w);
    }

    const int s0 = blockIdx.x * 8;
    const int w  = blockIdx.y;

    if (w == 0) {   // init out rows with bias (node-2 atomically accumulates)
        const float bb = bo[j];
        #pragma unroll
        for (int r = 0; r < 8; ++r)
            outbuf[(s0 + r) * DMODEL + j] = bb;
    }

    const float *X, *W, *bias; float* outp; float scale;
    if (w == 0)      { X = query;  W = Wq; bias = bq; outp = qhp; scale = QSCALE; }
    else if (w == 1) { X = key_in; W = Wk; bias = bk; outp = khp; scale = 1.0f; }
    else             { X = value;  W = Wv; bias = bv; outp = vhp; scale = 1.0f; }

    __shared__ __align__(16) float xs[8][DMODEL];     // 8KB
    __shared__ __align__(16) float ws[2][32 * DMODEL]; // 64KB (dbuf, 32k x 256c)

    {
        float* xsf = &xs[0][0];
        const float* Xp = X + s0 * DMODEL;
        const int i0 = j * 8;
        *(float4*)&xsf[i0]     = *(const float4*)&Xp[i0];
        *(float4*)&xsf[i0 + 4] = *(const float4*)&Xp[i0 + 4];

        #pragma unroll
        for (int t = 0; t < 8; ++t)
            *(float4*)&ws[0][t * 1024 + j * 4] =
                *(const float4*)&W[t * 1024 + j * 4];
    }
    __syncthreads();

    const int j0 = (j & 63) * 4;        // 4 consecutive output cols
    const int r0 = (j >> 6) * 2;        // 2 rows (wave-uniform -> broadcast)

    float4 acc0 = make_float4(0.f, 0.f, 0.f, 0.f);
    float4 acc1 = make_float4(0.f, 0.f, 0.f, 0.f);
    int cur = 0;

    for (int c = 0; c < 8; ++c) {
        float4 wreg[8];
        if (c < 7) {
            const float* Wc = W + (c + 1) * 8192;
            #pragma unroll
            for (int t = 0; t < 8; ++t)
                wreg[t] = *(const float4*)&Wc[t * 1024 + j * 4];
        }

        const float* wb = &ws[cur][0];
        #pragma unroll
        for (int k4 = 0; k4 < 8; ++k4) {
            const int kb = c * 32 + k4 * 4;
            float4 x0 = *(const float4*)&xs[r0 + 0][kb];
            float4 x1 = *(const float4*)&xs[r0 + 1][kb];
            float4 w0 = *(const float4*)&wb[(k4 * 4 + 0) * DMODEL + j0];
            float4 w1 = *(const float4*)&wb[(k4 * 4 + 1) * DMODEL + j0];
            float4 w2 = *(const float4*)&wb[(k4 * 4 + 2) * DMODEL + j0];
            float4 w3 = *(const float4*)&wb[(k4 * 4 + 3) * DMODEL + j0];
            acc0.x = fmaf(x0.x, w0.x, acc0.x); acc0.y = fmaf(x0.x, w0.y, acc0.y);
            acc0.z = fmaf(x0.x, w0.z, acc0.z); acc0.w = fmaf(x0.x, w0.w, acc0.w);
            acc0.x = fmaf(x0.y, w1.x, acc0.x); acc0.y = fmaf(x0.y, w1.y, acc0.y);
            acc0.z = fmaf(x0.y, w1.z, acc0.z); acc0.w = fmaf(x0.y, w1.w, acc0.w);
            acc0.x = fmaf(x0.z, w2.x, acc0.x); acc0.y = fmaf(x0.z, w2.y, acc0.y);
            acc0.z = fmaf(x0.z, w2.z, acc0.z); acc0.w = fmaf(x0.z, w2.w, acc0.w);
            acc0.x = fmaf(x0.w, w3.x, acc0.x); acc0.y = fmaf(x0.w, w3.y, acc0.y);
            acc0.z = fmaf(x0.w, w3.z, acc0.z); acc0.w = fmaf(x0.w, w3.w, acc0.w);
            acc1.x = fmaf(x1.x, w0.x, acc1.x); acc1.y = fmaf(x1.x, w0.y, acc1.y);
            acc1.z = fmaf(x1.x, w0.z, acc1.z); acc1.w = fmaf(x1.x, w0.w, acc1.w);
            acc1.x = fmaf(x1.y, w1.x, acc1.x); acc1.y = fmaf(x1.y, w1.y, acc1.y);
            acc1.z = fmaf(x1.y, w1.z, acc1.z); acc1.w = fmaf(x1.y, w1.w, acc1.w);
            acc1.x = fmaf(x1.z, w2.x, acc1.x); acc1.y = fmaf(x1.z, w2.y, acc1.y);
            acc1.z = fmaf(x1.z, w2.z, acc1.z); acc1.w = fmaf(x1.z, w2.w, acc1.w);
            acc1.x = fmaf(x1.w, w3.x, acc1.x); acc1.y = fmaf(x1.w, w3.y, acc1.y);
            acc1.z = fmaf(x1.w, w3.z, acc1.z); acc1.w = fmaf(x1.w, w3.w, acc1.w);
        }

        if (c < 7) {
            float* wd = &ws[cur ^ 1][0];
            #pragma unroll
            for (int t = 0; t < 8; ++t)
                *(float4*)&wd[t * 1024 + j * 4] = wreg[t];
            __syncthreads();
            cur ^= 1;
        }
    }

    const float4 bb = *(const float4*)&bias[j0];
    const int h = j0 >> 5, d = j0 & 31;
    {
        float4 o0, o1;
        o0.x = (acc0.x + bb.x) * scale; o0.y = (acc0.y + bb.y) * scale;
        o0.z = (acc0.z + bb.z) * scale; o0.w = (acc0.w + bb.w) * scale;
        o1.x = (acc1.x + bb.x) * scale; o1.y = (acc1.y + bb.y) * scale;
        o1.z = (acc1.z + bb.z) * scale; o1.w = (acc1.w + bb.w) * scale;
        *(float4*)&outp[h * (SQ * DHD) + (s0 + r0 + 0) * DHD + d] = o0;
        *(float4*)&outp[h * (SQ * DHD) + (s0 + r0 + 1) * DHD + d] = o1;
    }
}

// ---------------------------------------------------------------------------
// Node 2 (v4): p-in-register PV, V transposed, 1 barrier/chunk.
// QK mapping unchanged (qrt=(utid&15)*2, qct=(utid>>4)*4). PV uses the SAME
// thread tile: 2 rows x 4 cols x all 32 dims, acc[2][32] in regs, reading
// Vt[d][qct] b128 (4 distinct addrs/wave -> 16-lane broadcast, conflict-free,
// same pattern as QK's Ks reads). No Ps array, no QK->PV handoff -> 1 barrier.
// Epilogue: shfl_xor(16/32) in-wave col-group reduce -> 8-slab LDS reduce.
// v3 was 23.2us; per-chunk removes 8 conflicted Ps reads + 2 writes + 1 barrier.
// ---------------------------------------------------------------------------
__global__ __launch_bounds__(512) void attn2(
    const float* __restrict__ qh, const float* __restrict__ kh,
    const float* __restrict__ vh, const int* __restrict__ aidx,
    const float* __restrict__ mask, const float* __restrict__ Wo,
    float* __restrict__ scores_out, float* __restrict__ out, int M)
{
    __shared__ __align__(16) float Ks[2][2][32][68];   // [unit][buf][d][c] 69.6KB
    __shared__ __align__(16) float Vt[2][2][32][68];   // [unit][buf][d][c] 69.6KB
    __shared__ float dot0s[32];
    __shared__ float invL[32];

    const int b    = blockIdx.x;
    const int half = blockIdx.y;
    const int h    = blockIdx.z;
    const int s0b  = b * 64;
    const int s0   = s0b + half * 32;
    const int tid  = threadIdx.x;
    const int u    = tid >> 8;        // unit 0/1
    const int utid = tid & 255;
    const int NCH2 = M / 128;         // chunks per unit (6)

    const int qrt = (utid & 15) * 2;  // 2 rows
    const int qct = (utid >> 4) * 4;  // 4 cols (c-quad)
    const int c   = utid & 63;        // staging token within chunk
    const int sg  = utid >> 6;        // staging dim group 0..3
    const int d4a = sg * 4;
    const int d4b = 16 + sg * 4;

    const float* mrow = &mask[s0b * M];
    const int*   arow = &aidx[s0b * M];
    float*       srow = &scores_out[(h * SQ + s0) * M];

    // ---- Q rows (qrt, qrt+1) fully in registers ----
    float qr0[32], qr1[32];
    {
        const float* qp = &qh[(h * SQ + s0 + qrt) * DHD];
        #pragma unroll
        for (int d4 = 0; d4 < DHD; d4 += 4) {
            float4 a  = *(const float4*)&qp[d4];
            float4 b4 = *(const float4*)&qp[DHD + d4];
            qr0[d4] = a.x;  qr0[d4+1] = a.y;  qr0[d4+2] = a.z;  qr0[d4+3] = a.w;
            qr1[d4] = b4.x; qr1[d4+1] = b4.y; qr1[d4+2] = b4.z; qr1[d4+3] = b4.w;
        }
    }

    // dot0[r] = q_row . k[token 0]  (chunk-invariant; for padded chunks)
    if (tid < 16) {
        const float* k0 = &kh[h * SQ * DHD];
        float a0 = 0.f, a1 = 0.f;
        #pragma unroll
        for (int d = 0; d < DHD; ++d) {
            const float kv = k0[d];
            a0 = fmaf(qr0[d], kv, a0);
            a1 = fmaf(qr1[d], kv, a1);
        }
        dot0s[qrt] = a0; dot0s[qrt + 1] = a1;
    }

    // ---- prologue: stage chunk 0 (K and V both transposed) ----
    float mv_cur = mrow[(u * NCH2) * 64];
    bool  val_cur = mv_cur > -0.5f;
    if (val_cur) {
        const int t0 = arow[(u * NCH2) * 64];
        const float* kp = &kh[(h * SQ + t0 + c) * DHD];
        const float* vp = &vh[(h * SQ + t0 + c) * DHD];
        float4 ka = *(const float4*)&kp[d4a];
        float4 kb = *(const float4*)&kp[d4b];
        float4 va = *(const float4*)&vp[d4a];
        float4 vb = *(const float4*)&vp[d4b];
        Ks[u][0][d4a+0][c] = ka.x; Ks[u][0][d4a+1][c] = ka.y;
        Ks[u][0][d4a+2][c] = ka.z; Ks[u][0][d4a+3][c] = ka.w;
        Ks[u][0][d4b+0][c] = kb.x; Ks[u][0][d4b+1][c] = kb.y;
        Ks[u][0][d4b+2][c] = kb.z; Ks[u][0][d4b+3][c] = kb.w;
        Vt[u][0][d4a+0][c] = va.x; Vt[u][0][d4a+1][c] = va.y;
        Vt[u][0][d4a+2][c] = va.z; Vt[u][0][d4a+3][c] = va.w;
        Vt[u][0][d4b+0][c] = vb.x; Vt[u][0][d4b+1][c] = vb.y;
        Vt[u][0][d4b+2][c] = vb.z; Vt[u][0][d4b+3][c] = vb.w;
    }
    __syncthreads();

    float a0s[32], a1s[32];
    #pragma unroll
    for (int d = 0; d < 32; ++d) { a0s[d] = 0.f; a1s[d] = 0.f; }
    float rps0 = 0.f, rps1 = 0.f;
    int cur = 0;

    for (int ci = 0; ci < NCH2; ++ci) {
        const int m0 = (u * NCH2 + ci) * 64;

        // prefetch next chunk into registers (latency hides under QK+PV)
        bool  val_nxt = false;
        float mv_nxt  = 0.f;
        float4 ka, kb, va, vb;
        if (ci + 1 < NCH2) {
            mv_nxt  = mrow[m0 + 64];
            val_nxt = mv_nxt > -0.5f;
            if (val_nxt) {
                const int t0 = arow[m0 + 64];
                const float* kp = &kh[(h * SQ + t0 + c) * DHD];
                const float* vp = &vh[(h * SQ + t0 + c) * DHD];
                ka = *(const float4*)&kp[d4a];
                kb = *(const float4*)&kp[d4b];
                va = *(const float4*)&vp[d4a];
                vb = *(const float4*)&vp[d4b];
            }
        }

        if (val_cur) {
            // QK^T (K from LDS, Q from regs)
            const float* Kb = &Ks[u][cur][0][qct];
            float sc[2][4] = {};
            #pragma unroll
            for (int kk = 0; kk < 32; ++kk) {
                float4 b4 = *(const float4*)&Kb[kk * 68];
                sc[0][0] = fmaf(qr0[kk], b4.x, sc[0][0]);
                sc[0][1] = fmaf(qr0[kk], b4.y, sc[0][1]);
                sc[0][2] = fmaf(qr0[kk], b4.z, sc[0][2]);
                sc[0][3] = fmaf(qr0[kk], b4.w, sc[0][3]);
                sc[1][0] = fmaf(qr1[kk], b4.x, sc[1][0]);
                sc[1][1] = fmaf(qr1[kk], b4.y, sc[1][1]);
                sc[1][2] = fmaf(qr1[kk], b4.z, sc[1][2]);
                sc[1][3] = fmaf(qr1[kk], b4.w, sc[1][3]);
            }
            *(float4*)&srow[(qrt + 0) * M + m0 + qct] =
                make_float4(sc[0][0], sc[0][1], sc[0][2], sc[0][3]);
            *(float4*)&srow[(qrt + 1) * M + m0 + qct] =
                make_float4(sc[1][0], sc[1][1], sc[1][2], sc[1][3]);
            float e0[4], e1[4];
            #pragma unroll
            for (int t = 0; t < 4; ++t) {
                e0[t] = __expf(sc[0][t] - PSHIFT);
                e1[t] = __expf(sc[1][t] - PSHIFT);
            }
            rps0 += (e0[0] + e0[1]) + (e0[2] + e0[3]);
            rps1 += (e1[0] + e1[1]) + (e1[2] + e1[3]);

            // PV: p in regs, V^T from LDS (broadcast pattern, conflict-free)
            const float* Vb = &Vt[u][cur][0][qct];
            #pragma unroll
            for (int d = 0; d < 32; ++d) {
                float4 v = *(const float4*)&Vb[d * 68];
                a0s[d] = fmaf(e0[0], v.x, fmaf(e0[1], v.y,
                         fmaf(e0[2], v.z, fmaf(e0[3], v.w, a0s[d]))));
                a1s[d] = fmaf(e1[0], v.x, fmaf(e1[1], v.y,
                         fmaf(e1[2], v.z, fmaf(e1[3], v.w, a1s[d]))));
            }
        } else {
            #pragma unroll
            for (int i = 0; i < 8; ++i) {
                const int e = utid + i * 256;
                const int r = e >> 6, cc = e & 63;
                srow[r * M + m0 + cc] = dot0s[r] + mv_cur;
            }
        }

        // write prefetched chunk into the other buffer (transposed)
        if (val_nxt) {
            Ks[u][cur^1][d4a+0][c] = ka.x; Ks[u][cur^1][d4a+1][c] = ka.y;
            Ks[u][cur^1][d4a+2][c] = ka.z; Ks[u][cur^1][d4a+3][c] = ka.w;
            Ks[u][cur^1][d4b+0][c] = kb.x; Ks[u][cur^1][d4b+1][c] = kb.y;
            Ks[u][cur^1][d4b+2][c] = kb.z; Ks[u][cur^1][d4b+3][c] = kb.w;
            Vt[u][cur^1][d4a+0][c] = va.x; Vt[u][cur^1][d4a+1][c] = va.y;
            Vt[u][cur^1][d4a+2][c] = va.z; Vt[u][cur^1][d4a+3][c] = va.w;
            Vt[u][cur^1][d4b+0][c] = vb.x; Vt[u][cur^1][d4b+1][c] = vb.y;
            Vt[u][cur^1][d4b+2][c] = vb.z; Vt[u][cur^1][d4b+3][c] = vb.w;
        }
        __syncthreads();   // single barrier: next buffer staged, cur consumed

        val_cur = val_nxt; mv_cur = mv_nxt; cur ^= 1;
    }

    // ---- epilogue ----
    // in-wave reduce over the 4 c-quad groups (lanes ^16, ^32; rp preserved)
    #pragma unroll
    for (int d = 0; d < 32; ++d) {
        a0s[d] += __shfl_xor(a0s[d], 16);
        a0s[d] += __shfl_xor(a0s[d], 32);
        a1s[d] += __shfl_xor(a1s[d], 16);
        a1s[d] += __shfl_xor(a1s[d], 32);
    }
    rps0 += __shfl_xor(rps0, 16); rps0 += __shfl_xor(rps0, 32);
    rps1 += __shfl_xor(rps1, 16); rps1 += __shfl_xor(rps1, 32);

    // 8 wave-slabs -> LDS (overlay on Ks; all Ks reads done at loop barrier)
    float* vacc = &Ks[0][0][0][0];            // [8][32][36] = 9216 floats
    float* rsum = vacc + 8 * 32 * 36;         // [8][32] = 256 floats (fits Ks)
    const int wv = tid >> 6, lane = tid & 63;
    if (lane < 16) {
        const int rp2 = lane * 2;             // rows rp2, rp2+1 (== qrt)
        float* base0 = vacc + (wv * 32 + rp2) * 36;
        #pragma unroll
        for (int dq = 0; dq < 8; ++dq) {
            *(float4*)&base0[dq * 4] =
                make_float4(a0s[dq*4+0], a0s[dq*4+1], a0s[dq*4+2], a0s[dq*4+3]);
            *(float4*)&base0[36 + dq * 4] =
                make_float4(a1s[dq*4+0], a1s[dq*4+1], a1s[dq*4+2], a1s[dq*4+3]);
        }
        rsum[wv * 32 + rp2]     = rps0;
        rsum[wv * 32 + rp2 + 1] = rps1;
    }
    __syncthreads();

    if (tid < 32) {
        float pt = 0.f;
        #pragma unroll
        for (int s2 = 0; s2 < 8; ++s2) pt += rsum[s2 * 32 + tid];
        invL[tid] = 1.0f / pt;
    }
    __syncthreads();

    float* ctxn = &Vt[0][0][0][0];            // [32][36] overlay on Vt
    if (tid < 256) {
        const int r = tid & 31, dq = tid >> 5;
        float4 sum = make_float4(0.f, 0.f, 0.f, 0.f);
        #pragma unroll
        for (int s = 0; s < 8; ++s) {
            float4 v = *(const float4*)&vacc[(s * 32 + r) * 36 + dq * 4];
            sum.x += v.x; sum.y += v.y; sum.z += v.z; sum.w += v.w;
        }
        const float il = invL[r];
        sum.x *= il; sum.y *= il; sum.z *= il; sum.w *= il;
        *(float4*)&ctxn[r * 36 + dq * 4] = sum;
    }
    __syncthreads();

    // ---- per-head outproj partial, atomically accumulated into out ----
    {
        const int jc = tid & 255, rg = tid >> 8;
        float wo[32];
        #pragma unroll
        for (int k = 0; k < 32; ++k)
            wo[k] = Wo[(h * DHD + k) * DMODEL + jc];
        for (int rr = rg * 16; rr < rg * 16 + 16; ++rr) {
            float a = 0.f;
            #pragma unroll
            for (int k4 = 0; k4 < 8; ++k4) {
                float4 cv = *(const float4*)&ctxn[rr * 36 + k4 * 4];
                a = fmaf(cv.x, wo[k4 * 4 + 0], a);
                a = fmaf(cv.y, wo[k4 * 4 + 1], a);
                a = fmaf(cv.z, wo[k4 * 4 + 2], a);
                a = fmaf(cv.w, wo[k4 * 4 + 3], a);
            }
            atomicAdd(&out[(s0 + rr) * DMODEL + jc], a);
        }
    }
}

extern "C" void kernel_launch(void* const* d_in, const int* in_sizes, int n_in,
                              void* d_out, int out_size, void* d_ws, size_t ws_size,
                              hipStream_t stream)
{
    const float* query  = (const float*)d_in[0];
    const float* value  = (const float*)d_in[1];
    const float* key_in = (const float*)d_in[2];
    const float* Wq = (const float*)d_in[3];
    const float* bq = (const float*)d_in[4];
    const float* Wk = (const float*)d_in[5];
    const float* bk = (const float*)d_in[6];
    const float* Wv = (const float*)d_in[7];
    const float* bv = (const float*)d_in[8];
    const float* Wo = (const float*)d_in[9];
    const float* bo = (const float*)d_in[10];
    const int*   aidx = (const int*)d_in[11];
    const float* mask = (const float*)d_in[12];

    const int M = in_sizes[11] / SQ;   // 768

    float* out        = (float*)d_out;
    float* scores_out = out + SQ * DMODEL;
    float* idx_out    = scores_out + NH * SQ * M;

    float* ws  = (float*)d_ws;
    float* qhp = ws;
    float* khp = qhp + NH * SQ * DHD;
    float* vhp = khp + NH * SQ * DHD;

    proj3<<<dim3(96, 3), 256, 0, stream>>>(
        query, value, key_in, Wq, bq, Wk, bk, Wv, bv,
        bo, out, aidx, idx_out, qhp, khp, vhp);

    attn2<<<dim3(NB, 2, NH), 512, 0, stream>>>(
        qhp, khp, vhp, aidx, mask, Wo, scores_out, out, M);
}

// Round 10
// 57.563 us; speedup vs baseline: 1.2162x; 1.0431x over previous
//
#include <hip/hip_runtime.h>
#include <math.h>

#define SQ 768
#define DMODEL 256
#define NH 8
#define DHD 32
#define NB 12                       // query blocks (SQ/64)
#define QSCALE 0.1767766952966369f  // 32^-0.5
#define PSHIFT 8.0f                 // fixed softmax shift (math-equiv to max-sub)

// ---------------------------------------------------------------------------
// Ledger: F=5.8us, proj3_v6=20.0us, attn2_v3=23.2us (= its LDS-issue model:
// 55.7K cyc @2.4GHz with both units sharing the CU LDS pipe — attn2 is
// genuinely LDS-issue bound; no clock mystery).
// R9: attn2_v4 (p-in-reg, acc 64 regs) SPILLED: VGPR capped 128, scratch
// FETCH 14.4MB, VALUBusy 13%, 44us. Lesson: count the register budget.
//
// Node 1 (v6, byte-identical to R7): W staged through LDS, 8 dbuf chunks.
// ---------------------------------------------------------------------------
__global__ __launch_bounds__(256) void proj3(
    const float* __restrict__ query, const float* __restrict__ value,
    const float* __restrict__ key_in,
    const float* __restrict__ Wq, const float* __restrict__ bq,
    const float* __restrict__ Wk, const float* __restrict__ bk,
    const float* __restrict__ Wv, const float* __restrict__ bv,
    const float* __restrict__ bo, float* __restrict__ outbuf,
    const int* __restrict__ aidx, float* __restrict__ idx_out,
    float* __restrict__ qhp, float* __restrict__ khp, float* __restrict__ vhp)
{
    const int j = threadIdx.x;

    // idx -> float copy: 288 blocks * 256 threads * 8 elems == 589824 exactly
    {
        const int bidf = blockIdx.y * 96 + blockIdx.x;
        const int i0 = (bidf * 256 + j) * 8;
        int4 a = *(const int4*)&aidx[i0];
        int4 b = *(const int4*)&aidx[i0 + 4];
        *(float4*)&idx_out[i0] =
            make_float4((float)a.x, (float)a.y, (float)a.z, (float)a.w);
        *(float4*)&idx_out[i0 + 4] =
            make_float4((float)b.x, (float)b.y, (float)b.z, (float)b.w);
    }

    const int s0 = blockIdx.x * 8;
    const int w  = blockIdx.y;

    if (w == 0) {   // init out rows with bias (node-2 atomically accumulates)
        const float bb = bo[j];
        #pragma unroll
        for (int r = 0; r < 8; ++r)
            outbuf[(s0 + r) * DMODEL + j] = bb;
    }

    const float *X, *W, *bias; float* outp; float scale;
    if (w == 0)      { X = query;  W = Wq; bias = bq; outp = qhp; scale = QSCALE; }
    else if (w == 1) { X = key_in; W = Wk; bias = bk; outp = khp; scale = 1.0f; }
    else             { X = value;  W = Wv; bias = bv; outp = vhp; scale = 1.0f; }

    __shared__ __align__(16) float xs[8][DMODEL];     // 8KB
    __shared__ __align__(16) float ws[2][32 * DMODEL]; // 64KB (dbuf, 32k x 256c)

    {
        float* xsf = &xs[0][0];
        const float* Xp = X + s0 * DMODEL;
        const int i0 = j * 8;
        *(float4*)&xsf[i0]     = *(const float4*)&Xp[i0];
        *(float4*)&xsf[i0 + 4] = *(const float4*)&Xp[i0 + 4];

        #pragma unroll
        for (int t = 0; t < 8; ++t)
            *(float4*)&ws[0][t * 1024 + j * 4] =
                *(const float4*)&W[t * 1024 + j * 4];
    }
    __syncthreads();

    const int j0 = (j & 63) * 4;        // 4 consecutive output cols
    const int r0 = (j >> 6) * 2;        // 2 rows (wave-uniform -> broadcast)

    float4 acc0 = make_float4(0.f, 0.f, 0.f, 0.f);
    float4 acc1 = make_float4(0.f, 0.f, 0.f, 0.f);
    int cur = 0;

    for (int c = 0; c < 8; ++c) {
        float4 wreg[8];
        if (c < 7) {
            const float* Wc = W + (c + 1) * 8192;
            #pragma unroll
            for (int t = 0; t < 8; ++t)
                wreg[t] = *(const float4*)&Wc[t * 1024 + j * 4];
        }

        const float* wb = &ws[cur][0];
        #pragma unroll
        for (int k4 = 0; k4 < 8; ++k4) {
            const int kb = c * 32 + k4 * 4;
            float4 x0 = *(const float4*)&xs[r0 + 0][kb];
            float4 x1 = *(const float4*)&xs[r0 + 1][kb];
            float4 w0 = *(const float4*)&wb[(k4 * 4 + 0) * DMODEL + j0];
            float4 w1 = *(const float4*)&wb[(k4 * 4 + 1) * DMODEL + j0];
            float4 w2 = *(const float4*)&wb[(k4 * 4 + 2) * DMODEL + j0];
            float4 w3 = *(const float4*)&wb[(k4 * 4 + 3) * DMODEL + j0];
            acc0.x = fmaf(x0.x, w0.x, acc0.x); acc0.y = fmaf(x0.x, w0.y, acc0.y);
            acc0.z = fmaf(x0.x, w0.z, acc0.z); acc0.w = fmaf(x0.x, w0.w, acc0.w);
            acc0.x = fmaf(x0.y, w1.x, acc0.x); acc0.y = fmaf(x0.y, w1.y, acc0.y);
            acc0.z = fmaf(x0.y, w1.z, acc0.z); acc0.w = fmaf(x0.y, w1.w, acc0.w);
            acc0.x = fmaf(x0.z, w2.x, acc0.x); acc0.y = fmaf(x0.z, w2.y, acc0.y);
            acc0.z = fmaf(x0.z, w2.z, acc0.z); acc0.w = fmaf(x0.z, w2.w, acc0.w);
            acc0.x = fmaf(x0.w, w3.x, acc0.x); acc0.y = fmaf(x0.w, w3.y, acc0.y);
            acc0.z = fmaf(x0.w, w3.z, acc0.z); acc0.w = fmaf(x0.w, w3.w, acc0.w);
            acc1.x = fmaf(x1.x, w0.x, acc1.x); acc1.y = fmaf(x1.x, w0.y, acc1.y);
            acc1.z = fmaf(x1.x, w0.z, acc1.z); acc1.w = fmaf(x1.x, w0.w, acc1.w);
            acc1.x = fmaf(x1.y, w1.x, acc1.x); acc1.y = fmaf(x1.y, w1.y, acc1.y);
            acc1.z = fmaf(x1.y, w1.z, acc1.z); acc1.w = fmaf(x1.y, w1.w, acc1.w);
            acc1.x = fmaf(x1.z, w2.x, acc1.x); acc1.y = fmaf(x1.z, w2.y, acc1.y);
            acc1.z = fmaf(x1.z, w2.z, acc1.z); acc1.w = fmaf(x1.z, w2.w, acc1.w);
            acc1.x = fmaf(x1.w, w3.x, acc1.x); acc1.y = fmaf(x1.w, w3.y, acc1.y);
            acc1.z = fmaf(x1.w, w3.z, acc1.z); acc1.w = fmaf(x1.w, w3.w, acc1.w);
        }

        if (c < 7) {
            float* wd = &ws[cur ^ 1][0];
            #pragma unroll
            for (int t = 0; t < 8; ++t)
                *(float4*)&wd[t * 1024 + j * 4] = wreg[t];
            __syncthreads();
            cur ^= 1;
        }
    }

    const float4 bb = *(const float4*)&bias[j0];
    const int h = j0 >> 5, d = j0 & 31;
    {
        float4 o0, o1;
        o0.x = (acc0.x + bb.x) * scale; o0.y = (acc0.y + bb.y) * scale;
        o0.z = (acc0.z + bb.z) * scale; o0.w = (acc0.w + bb.w) * scale;
        o1.x = (acc1.x + bb.x) * scale; o1.y = (acc1.y + bb.y) * scale;
        o1.z = (acc1.z + bb.z) * scale; o1.w = (acc1.w + bb.w) * scale;
        *(float4*)&outp[h * (SQ * DHD) + (s0 + r0 + 0) * DHD + d] = o0;
        *(float4*)&outp[h * (SQ * DHD) + (s0 + r0 + 1) * DHD + d] = o1;
    }
}

// ---------------------------------------------------------------------------
// Node 2 (v5): v3 (23.2us, LDS-issue bound) with ONE change — PV retile
// 2r x 8d x 16c -> 4r x 8d x 8c: per thread per chunk 8 Ps-b128 + 16 Vs-b128
// = 24 LDS reads / 256 FMA (was 40). acc = 32 floats (fits; v4's 64 spilled).
// Epilogue: shfl_xor(32) folds cgp pairs -> identical 8-slab LDS reduce.
// launch_bounds(512,2) allows 256 VGPR (kills the 128-cap spill heuristic).
// ---------------------------------------------------------------------------
__global__ __launch_bounds__(512, 2) void attn2(
    const float* __restrict__ qh, const float* __restrict__ kh,
    const float* __restrict__ vh, const int* __restrict__ aidx,
    const float* __restrict__ mask, const float* __restrict__ Wo,
    float* __restrict__ scores_out, float* __restrict__ out, int M)
{
    __shared__ __align__(16) float Ks[2][2][32][68];   // [unit][buf][d][c]
    __shared__ __align__(16) float Vs[2][2][64][36];   // [unit][buf][c][d]
    __shared__ __align__(16) float Ps[2][32][68];      // [unit][row][c]
    __shared__ float dot0s[32];
    __shared__ float invL[32];

    const int b    = blockIdx.x;
    const int half = blockIdx.y;
    const int h    = blockIdx.z;
    const int s0b  = b * 64;
    const int s0   = s0b + half * 32;
    const int tid  = threadIdx.x;
    const int u    = tid >> 8;        // unit 0/1
    const int utid = tid & 255;
    const int NCH2 = M / 128;         // chunks per unit

    // QK mapping: 2 rows x 4 cols (unchanged from v3)
    const int qrt = (utid & 15) * 2;  // rows (2)
    const int qct = (utid >> 4) * 4;  // cols (4)
    // PV mapping (v5): 4 rows x 8 dims x 8-c slice
    const int rq  = utid & 7;             // row quad (rows 4rq..4rq+3)
    const int dgp = (utid >> 3) & 3;      // dim group (8 dims)
    const int cgp = utid >> 5;            // c group (8 c's); wave covers 2 cgp
    // staging mapping
    const int c   = utid & 63;        // token within chunk
    const int sg  = utid >> 6;        // staging dim group 0..3
    const int d4a = sg * 4;
    const int d4b = 16 + sg * 4;

    const float* mrow = &mask[s0b * M];
    const int*   arow = &aidx[s0b * M];
    float*       srow = &scores_out[(h * SQ + s0) * M];

    // ---- Q rows (qrt, qrt+1) fully in registers ----
    float qr0[32], qr1[32];
    {
        const float* qp = &qh[(h * SQ + s0 + qrt) * DHD];
        #pragma unroll
        for (int d4 = 0; d4 < DHD; d4 += 4) {
            float4 a  = *(const float4*)&qp[d4];
            float4 b4 = *(const float4*)&qp[DHD + d4];
            qr0[d4] = a.x;  qr0[d4+1] = a.y;  qr0[d4+2] = a.z;  qr0[d4+3] = a.w;
            qr1[d4] = b4.x; qr1[d4+1] = b4.y; qr1[d4+2] = b4.z; qr1[d4+3] = b4.w;
        }
    }

    // dot0[r] = q_row . k[token 0]  (chunk-invariant; for padded chunks)
    if (tid < 16) {
        const float* k0 = &kh[h * SQ * DHD];
        float a0 = 0.f, a1 = 0.f;
        #pragma unroll
        for (int d = 0; d < DHD; ++d) {
            const float kv = k0[d];
            a0 = fmaf(qr0[d], kv, a0);
            a1 = fmaf(qr1[d], kv, a1);
        }
        dot0s[qrt] = a0; dot0s[qrt + 1] = a1;
    }

    // ---- prologue: stage this unit's chunk 0 into buffer 0 ----
    float mv_cur = mrow[(u * NCH2) * 64];
    bool  val_cur = mv_cur > -0.5f;
    if (val_cur) {
        const int t0 = arow[(u * NCH2) * 64];
        const float* kp = &kh[(h * SQ + t0 + c) * DHD];
        const float* vp = &vh[(h * SQ + t0 + c) * DHD];
        float4 ka = *(const float4*)&kp[d4a];
        float4 kb = *(const float4*)&kp[d4b];
        Ks[u][0][d4a+0][c] = ka.x; Ks[u][0][d4a+1][c] = ka.y;
        Ks[u][0][d4a+2][c] = ka.z; Ks[u][0][d4a+3][c] = ka.w;
        Ks[u][0][d4b+0][c] = kb.x; Ks[u][0][d4b+1][c] = kb.y;
        Ks[u][0][d4b+2][c] = kb.z; Ks[u][0][d4b+3][c] = kb.w;
        *(float4*)&Vs[u][0][c][d4a] = *(const float4*)&vp[d4a];
        *(float4*)&Vs[u][0][c][d4b] = *(const float4*)&vp[d4b];
    }
    __syncthreads();

    // PV accumulators: 4 rows x 8 dims (c-slice partials, live across chunks)
    float4 accA[4], accB[4];
    #pragma unroll
    for (int i = 0; i < 4; ++i) {
        accA[i] = make_float4(0.f, 0.f, 0.f, 0.f);
        accB[i] = make_float4(0.f, 0.f, 0.f, 0.f);
    }
    float rps0 = 0.f, rps1 = 0.f;
    int cur = 0;

    for (int ci = 0; ci < NCH2; ++ci) {
        const int m0 = (u * NCH2 + ci) * 64;

        // issue next chunk's global loads early (latency hides under QK)
        bool  val_nxt = false;
        float mv_nxt  = 0.f;
        float4 ka, kb, va, vb;
        if (ci + 1 < NCH2) {
            mv_nxt  = mrow[m0 + 64];
            val_nxt = mv_nxt > -0.5f;
            if (val_nxt) {
                const int t0 = arow[m0 + 64];
                const float* kp = &kh[(h * SQ + t0 + c) * DHD];
                const float* vp = &vh[(h * SQ + t0 + c) * DHD];
                ka = *(const float4*)&kp[d4a];
                kb = *(const float4*)&kp[d4b];
                va = *(const float4*)&vp[d4a];
                vb = *(const float4*)&vp[d4b];
            }
        }

        // QK^T + scores + exp->Ps (K from LDS, Q from registers)
        if (val_cur) {
            const float* Kb = &Ks[u][cur][0][qct];
            float sc[2][4] = {};
            #pragma unroll
            for (int kk = 0; kk < 32; ++kk) {
                float4 b4 = *(const float4*)&Kb[kk * 68];
                sc[0][0] = fmaf(qr0[kk], b4.x, sc[0][0]);
                sc[0][1] = fmaf(qr0[kk], b4.y, sc[0][1]);
                sc[0][2] = fmaf(qr0[kk], b4.z, sc[0][2]);
                sc[0][3] = fmaf(qr0[kk], b4.w, sc[0][3]);
                sc[1][0] = fmaf(qr1[kk], b4.x, sc[1][0]);
                sc[1][1] = fmaf(qr1[kk], b4.y, sc[1][1]);
                sc[1][2] = fmaf(qr1[kk], b4.z, sc[1][2]);
                sc[1][3] = fmaf(qr1[kk], b4.w, sc[1][3]);
            }
            {
                *(float4*)&srow[(qrt + 0) * M + m0 + qct] =
                    make_float4(sc[0][0], sc[0][1], sc[0][2], sc[0][3]);
                float4 e;
                e.x = __expf(sc[0][0] - PSHIFT); e.y = __expf(sc[0][1] - PSHIFT);
                e.z = __expf(sc[0][2] - PSHIFT); e.w = __expf(sc[0][3] - PSHIFT);
                *(float4*)&Ps[u][qrt + 0][qct] = e;
                rps0 += (e.x + e.y) + (e.z + e.w);
            }
            {
                *(float4*)&srow[(qrt + 1) * M + m0 + qct] =
                    make_float4(sc[1][0], sc[1][1], sc[1][2], sc[1][3]);
                float4 e;
                e.x = __expf(sc[1][0] - PSHIFT); e.y = __expf(sc[1][1] - PSHIFT);
                e.z = __expf(sc[1][2] - PSHIFT); e.w = __expf(sc[1][3] - PSHIFT);
                *(float4*)&Ps[u][qrt + 1][qct] = e;
                rps1 += (e.x + e.y) + (e.z + e.w);
            }
        } else {
            #pragma unroll
            for (int i = 0; i < 8; ++i) {
                const int e = utid + i * 256;
                const int r = e >> 6, cc = e & 63;
                srow[r * M + m0 + cc] = dot0s[r] + mv_cur;
            }
        }

        // write prefetched chunk into the other buffer
        if (val_nxt) {
            Ks[u][cur^1][d4a+0][c] = ka.x; Ks[u][cur^1][d4a+1][c] = ka.y;
            Ks[u][cur^1][d4a+2][c] = ka.z; Ks[u][cur^1][d4a+3][c] = ka.w;
            Ks[u][cur^1][d4b+0][c] = kb.x; Ks[u][cur^1][d4b+1][c] = kb.y;
            Ks[u][cur^1][d4b+2][c] = kb.z; Ks[u][cur^1][d4b+3][c] = kb.w;
            *(float4*)&Vs[u][cur^1][c][d4a] = va;
            *(float4*)&Vs[u][cur^1][c][d4b] = vb;
        }
        __syncthreads();   // Ps visible + next buffer staged

        // PV accumulate (v5): rows 4rq..+3; dims dgp*8..+7; c's cgp*8..+7
        if (val_cur) {
            const float (*Vb)[36] = Vs[u][cur];
            const int r0q = rq * 4;
            const int c0 = cgp * 8;
            const int dd = dgp * 8;
            #pragma unroll
            for (int k = 0; k < 2; ++k) {           // 2 quads of 4 c's
                float4 p0 = *(const float4*)&Ps[u][r0q + 0][c0 + k * 4];
                float4 p1 = *(const float4*)&Ps[u][r0q + 1][c0 + k * 4];
                float4 p2 = *(const float4*)&Ps[u][r0q + 2][c0 + k * 4];
                float4 p3 = *(const float4*)&Ps[u][r0q + 3][c0 + k * 4];
                const float pv[4][4] = {
                    {p0.x, p0.y, p0.z, p0.w}, {p1.x, p1.y, p1.z, p1.w},
                    {p2.x, p2.y, p2.z, p2.w}, {p3.x, p3.y, p3.z, p3.w}};
                #pragma unroll
                for (int t = 0; t < 4; ++t) {
                    const int cc2 = c0 + k * 4 + t;
                    float4 v0 = *(const float4*)&Vb[cc2][dd];
                    float4 v1 = *(const float4*)&Vb[cc2][dd + 4];
                    #pragma unroll
                    for (int i = 0; i < 4; ++i) {
                        accA[i].x = fmaf(pv[i][t], v0.x, accA[i].x);
                        accA[i].y = fmaf(pv[i][t], v0.y, accA[i].y);
                        accA[i].z = fmaf(pv[i][t], v0.z, accA[i].z);
                        accA[i].w = fmaf(pv[i][t], v0.w, accA[i].w);
                        accB[i].x = fmaf(pv[i][t], v1.x, accB[i].x);
                        accB[i].y = fmaf(pv[i][t], v1.y, accB[i].y);
                        accB[i].z = fmaf(pv[i][t], v1.z, accB[i].z);
                        accB[i].w = fmaf(pv[i][t], v1.w, accB[i].w);
                    }
                }
            }
        }
        __syncthreads();   // Ps / Vs[cur] consumed; next iter may overwrite

        val_cur = val_nxt; mv_cur = mv_nxt; cur ^= 1;
    }

    // ---- epilogue ----
    // fold the wave's two cgp slices (lanes ^32) -> 4 slabs/unit, 8 total
    #pragma unroll
    for (int i = 0; i < 4; ++i) {
        accA[i].x += __shfl_xor(accA[i].x, 32);
        accA[i].y += __shfl_xor(accA[i].y, 32);
        accA[i].z += __shfl_xor(accA[i].z, 32);
        accA[i].w += __shfl_xor(accA[i].w, 32);
        accB[i].x += __shfl_xor(accB[i].x, 32);
        accB[i].y += __shfl_xor(accB[i].y, 32);
        accB[i].z += __shfl_xor(accB[i].z, 32);
        accB[i].w += __shfl_xor(accB[i].w, 32);
    }

    float* vacc = &Vs[0][0][0][0];              // vacc[8][32][36] overlay
    float* rsum = &Ps[0][0][0];                 // rsum[32][32] overlay
    {
        const int lane = tid & 63;
        if (lane < 32) {
            const int s = u * 4 + (utid >> 6);  // unit * 4 + wave-in-unit
            const int rr0 = (lane & 7) * 4;
            const int ddw = ((lane >> 3) & 3) * 8;
            float* base = vacc + (s * 32 + rr0) * 36 + ddw;
            #pragma unroll
            for (int i = 0; i < 4; ++i) {
                *(float4*)&base[i * 36 + 0] = accA[i];
                *(float4*)&base[i * 36 + 4] = accB[i];
            }
        }
        const int qg = utid >> 4;               // 0..15
        rsum[(u * 16 + qg) * 32 + qrt]     = rps0;
        rsum[(u * 16 + qg) * 32 + qrt + 1] = rps1;
    }
    __syncthreads();

    if (tid < 32) {
        float pt = 0.f;
        #pragma unroll
        for (int s2 = 0; s2 < 32; ++s2) pt += rsum[s2 * 32 + tid];
        invL[tid] = 1.0f / pt;
    }
    __syncthreads();

    float* ctxn = &Ks[0][0][0][0];              // ctxn[32][36] overlay
    if (tid < 256) {
        const int r = tid & 31, dq = tid >> 5;  // 8 dim-quads
        float4 sum = make_float4(0.f, 0.f, 0.f, 0.f);
        #pragma unroll
        for (int s = 0; s < 8; ++s) {
            float4 v = *(const float4*)&vacc[(s * 32 + r) * 36 + dq * 4];
            sum.x += v.x; sum.y += v.y; sum.z += v.z; sum.w += v.w;
        }
        const float il = invL[r];
        sum.x *= il; sum.y *= il; sum.z *= il; sum.w *= il;
        *(float4*)&ctxn[r * 36 + dq * 4] = sum;
    }
    __syncthreads();

    // ---- per-head outproj partial, atomically accumulated into out ----
    {
        const int jc = tid & 255, rg = tid >> 8;
        float wo[32];
        #pragma unroll
        for (int k = 0; k < 32; ++k)
            wo[k] = Wo[(h * DHD + k) * DMODEL + jc];
        for (int rr = rg * 16; rr < rg * 16 + 16; ++rr) {
            float a = 0.f;
            #pragma unroll
            for (int k4 = 0; k4 < 8; ++k4) {
                float4 cv = *(const float4*)&ctxn[rr * 36 + k4 * 4];
                a = fmaf(cv.x, wo[k4 * 4 + 0], a);
                a = fmaf(cv.y, wo[k4 * 4 + 1], a);
                a = fmaf(cv.z, wo[k4 * 4 + 2], a);
                a = fmaf(cv.w, wo[k4 * 4 + 3], a);
            }
            atomicAdd(&out[(s0 + rr) * DMODEL + jc], a);
        }
    }
}

extern "C" void kernel_launch(void* const* d_in, const int* in_sizes, int n_in,
                              void* d_out, int out_size, void* d_ws, size_t ws_size,
                              hipStream_t stream)
{
    const float* query  = (const float*)d_in[0];
    const float* value  = (const float*)d_in[1];
    const float* key_in = (const float*)d_in[2];
    const float* Wq = (const float*)d_in[3];
    const float* bq = (const float*)d_in[4];
    const float* Wk = (const float*)d_in[5];
    const float* bk = (const float*)d_in[6];
    const float* Wv = (const float*)d_in[7];
    const float* bv = (const float*)d_in[8];
    const float* Wo = (const float*)d_in[9];
    const float* bo = (const float*)d_in[10];
    const int*   aidx = (const int*)d_in[11];
    const float* mask = (const float*)d_in[12];

    const int M = in_sizes[11] / SQ;   // 768

    float* out        = (float*)d_out;
    float* scores_out = out + SQ * DMODEL;
    float* idx_out    = scores_out + NH * SQ * M;

    float* ws  = (float*)d_ws;
    float* qhp = ws;
    float* khp = qhp + NH * SQ * DHD;
    float* vhp = khp + NH * SQ * DHD;

    proj3<<<dim3(96, 3), 256, 0, stream>>>(
        query, value, key_in, Wq, bq, Wk, bk, Wv, bv,
        bo, out, aidx, idx_out, qhp, khp, vhp);

    attn2<<<dim3(NB, 2, NH), 512, 0, stream>>>(
        qhp, khp, vhp, aidx, mask, Wo, scores_out, out, M);
}

// Round 11
// 52.372 us; speedup vs baseline: 1.3367x; 1.0991x over previous
//
#include <hip/hip_runtime.h>
#include <math.h>

#define SQ 768
#define DMODEL 256
#define NH 8
#define DHD 32
#define NB 12                       // query blocks (SQ/64)
#define QSCALE 0.1767766952966369f  // 32^-0.5
#define PSHIFT 8.0f                 // fixed softmax shift (math-equiv to max-sub)

// ---------------------------------------------------------------------------
// Ledger: F=5.8us. attn2_v3=23.2us (best, LDS-model-consistent, reverted to
// byte-exact here). proj3_v6=20.0us at 288 blocks = 1.125 blocks/CU — its
// ~8.6us LDS issue sits under ~11us exposed latency at 1.1 waves/SIMD.
// R10 lesson: v5's PV retile hit a 4-way Ps bank conflict (445K) + spill —
// check bank math and register budget BEFORE benching.
//
// Node 1 (v7): v6 structure, 4 rows/block -> grid (192,3) = 576 blocks,
// LDS 64KB(W dbuf)+4KB(xs) = 68KB -> 2 blocks/CU resident (2 w/SIMD, 2x
// latency hiding vs v6). Thread = 2 rows x 2 cols: per k4 = 2 b128 x
// (wave-uniform broadcast) + 4 float2 w (stride-2 banks, 2-way = free)
// + 16 FMA. Staging identical to v6 (8 float4/thread/chunk).
// ---------------------------------------------------------------------------
__global__ __launch_bounds__(256) void proj3(
    const float* __restrict__ query, const float* __restrict__ value,
    const float* __restrict__ key_in,
    const float* __restrict__ Wq, const float* __restrict__ bq,
    const float* __restrict__ Wk, const float* __restrict__ bk,
    const float* __restrict__ Wv, const float* __restrict__ bv,
    const float* __restrict__ bo, float* __restrict__ outbuf,
    const int* __restrict__ aidx, float* __restrict__ idx_out,
    float* __restrict__ qhp, float* __restrict__ khp, float* __restrict__ vhp)
{
    const int j = threadIdx.x;

    // idx -> float copy: 576 blocks * 256 threads * 4 elems == 589824 exactly
    {
        const int bidf = blockIdx.y * 192 + blockIdx.x;
        const int i0 = (bidf * 256 + j) * 4;
        int4 v = *(const int4*)&aidx[i0];
        *(float4*)&idx_out[i0] =
            make_float4((float)v.x, (float)v.y, (float)v.z, (float)v.w);
    }

    const int s0 = blockIdx.x * 4;
    const int w  = blockIdx.y;

    if (w == 0) {   // init out rows with bias (node-2 atomically accumulates)
        const float bb = bo[j];
        #pragma unroll
        for (int r = 0; r < 4; ++r)
            outbuf[(s0 + r) * DMODEL + j] = bb;
    }

    const float *X, *W, *bias; float* outp; float scale;
    if (w == 0)      { X = query;  W = Wq; bias = bq; outp = qhp; scale = QSCALE; }
    else if (w == 1) { X = key_in; W = Wk; bias = bk; outp = khp; scale = 1.0f; }
    else             { X = value;  W = Wv; bias = bv; outp = vhp; scale = 1.0f; }

    __shared__ __align__(16) float xs[4][DMODEL];      // 4KB
    __shared__ __align__(16) float ws[2][32 * DMODEL]; // 64KB (dbuf, 32k x 256c)

    // stage X (4 rows) + W chunk 0, then barrier
    {
        float* xsf = &xs[0][0];
        const float* Xp = X + s0 * DMODEL;
        *(float4*)&xsf[j * 4] = *(const float4*)&Xp[j * 4];

        #pragma unroll
        for (int t = 0; t < 8; ++t)
            *(float4*)&ws[0][t * 1024 + j * 4] =
                *(const float4*)&W[t * 1024 + j * 4];
    }
    __syncthreads();

    const int j0 = (j & 127) * 2;       // 2 consecutive output cols
    const int r0 = (j >> 7) * 2;        // 2 rows (wave-uniform -> broadcast)

    float2 acc0 = make_float2(0.f, 0.f);
    float2 acc1 = make_float2(0.f, 0.f);
    int cur = 0;

    for (int c = 0; c < 8; ++c) {
        // issue next chunk's global loads early (hide latency under FMA)
        float4 wreg[8];
        if (c < 7) {
            const float* Wc = W + (c + 1) * 8192;
            #pragma unroll
            for (int t = 0; t < 8; ++t)
                wreg[t] = *(const float4*)&Wc[t * 1024 + j * 4];
        }

        // compute chunk c from LDS
        const float* wb = &ws[cur][0];
        #pragma unroll
        for (int k4 = 0; k4 < 8; ++k4) {
            const int kb = c * 32 + k4 * 4;
            float4 x0 = *(const float4*)&xs[r0 + 0][kb];
            float4 x1 = *(const float4*)&xs[r0 + 1][kb];
            float2 w0 = *(const float2*)&wb[(k4 * 4 + 0) * DMODEL + j0];
            float2 w1 = *(const float2*)&wb[(k4 * 4 + 1) * DMODEL + j0];
            float2 w2 = *(const float2*)&wb[(k4 * 4 + 2) * DMODEL + j0];
            float2 w3 = *(const float2*)&wb[(k4 * 4 + 3) * DMODEL + j0];
            acc0.x = fmaf(x0.x, w0.x, acc0.x); acc0.y = fmaf(x0.x, w0.y, acc0.y);
            acc0.x = fmaf(x0.y, w1.x, acc0.x); acc0.y = fmaf(x0.y, w1.y, acc0.y);
            acc0.x = fmaf(x0.z, w2.x, acc0.x); acc0.y = fmaf(x0.z, w2.y, acc0.y);
            acc0.x = fmaf(x0.w, w3.x, acc0.x); acc0.y = fmaf(x0.w, w3.y, acc0.y);
            acc1.x = fmaf(x1.x, w0.x, acc1.x); acc1.y = fmaf(x1.x, w0.y, acc1.y);
            acc1.x = fmaf(x1.y, w1.x, acc1.x); acc1.y = fmaf(x1.y, w1.y, acc1.y);
            acc1.x = fmaf(x1.z, w2.x, acc1.x); acc1.y = fmaf(x1.z, w2.y, acc1.y);
            acc1.x = fmaf(x1.w, w3.x, acc1.x); acc1.y = fmaf(x1.w, w3.y, acc1.y);
        }

        // write prefetched chunk into the other buffer, one barrier per chunk
        if (c < 7) {
            float* wd = &ws[cur ^ 1][0];
            #pragma unroll
            for (int t = 0; t < 8; ++t)
                *(float4*)&wd[t * 1024 + j * 4] = wreg[t];
            __syncthreads();
            cur ^= 1;
        }
    }

    const float2 bb = *(const float2*)&bias[j0];
    const int h = j0 >> 5, d = j0 & 31;
    {
        float2 o0, o1;
        o0.x = (acc0.x + bb.x) * scale; o0.y = (acc0.y + bb.y) * scale;
        o1.x = (acc1.x + bb.x) * scale; o1.y = (acc1.y + bb.y) * scale;
        *(float2*)&outp[h * (SQ * DHD) + (s0 + r0 + 0) * DHD + d] = o0;
        *(float2*)&outp[h * (SQ * DHD) + (s0 + r0 + 1) * DHD + d] = o1;
    }
}

// ---------------------------------------------------------------------------
// Node 2 (v3, byte-exact revert to R6/R7 kernel — measured 23.2us):
// Ps transposed [row][c]; PV register tile 2r x 8d x 16c; rps in-register
// during QK; 8-slab LDS reduce epilogue.
// ---------------------------------------------------------------------------
__global__ __launch_bounds__(512) void attn2(
    const float* __restrict__ qh, const float* __restrict__ kh,
    const float* __restrict__ vh, const int* __restrict__ aidx,
    const float* __restrict__ mask, const float* __restrict__ Wo,
    float* __restrict__ scores_out, float* __restrict__ out, int M)
{
    __shared__ __align__(16) float Ks[2][2][32][68];   // [unit][buf][d][c]
    __shared__ __align__(16) float Vs[2][2][64][36];   // [unit][buf][c][d]
    __shared__ __align__(16) float Ps[2][32][68];      // [unit][row][c]
    __shared__ float dot0s[32];
    __shared__ float invL[32];

    const int b    = blockIdx.x;
    const int half = blockIdx.y;
    const int h    = blockIdx.z;
    const int s0b  = b * 64;
    const int s0   = s0b + half * 32;
    const int tid  = threadIdx.x;
    const int u    = tid >> 8;        // unit 0/1
    const int utid = tid & 255;
    const int NCH2 = M / 128;         // chunks per unit

    // QK mapping: 2 rows x 4 cols
    const int qrt = (utid & 15) * 2;  // rows (2)
    const int qct = (utid >> 4) * 4;  // cols (4)
    // PV mapping: same 2 rows; 8 dims; 16-c slice
    const int rp  = utid & 15;            // row pair (rows 2rp, 2rp+1 == qrt)
    const int dg  = (utid >> 4) & 3;      // dim group (8 dims)
    const int cg  = utid >> 6;            // c group (16 c's)
    // staging mapping
    const int c   = utid & 63;        // token within chunk
    const int sg  = utid >> 6;        // staging dim group 0..3
    const int d4a = sg * 4;
    const int d4b = 16 + sg * 4;

    const float* mrow = &mask[s0b * M];
    const int*   arow = &aidx[s0b * M];
    float*       srow = &scores_out[(h * SQ + s0) * M];

    // ---- Q rows (qrt, qrt+1) fully in registers ----
    float qr0[32], qr1[32];
    {
        const float* qp = &qh[(h * SQ + s0 + qrt) * DHD];
        #pragma unroll
        for (int d4 = 0; d4 < DHD; d4 += 4) {
            float4 a  = *(const float4*)&qp[d4];
            float4 b4 = *(const float4*)&qp[DHD + d4];
            qr0[d4] = a.x;  qr0[d4+1] = a.y;  qr0[d4+2] = a.z;  qr0[d4+3] = a.w;
            qr1[d4] = b4.x; qr1[d4+1] = b4.y; qr1[d4+2] = b4.z; qr1[d4+3] = b4.w;
        }
    }

    // dot0[r] = q_row . k[token 0]  (chunk-invariant; for padded chunks)
    if (tid < 16) {
        const float* k0 = &kh[h * SQ * DHD];
        float a0 = 0.f, a1 = 0.f;
        #pragma unroll
        for (int d = 0; d < DHD; ++d) {
            const float kv = k0[d];
            a0 = fmaf(qr0[d], kv, a0);
            a1 = fmaf(qr1[d], kv, a1);
        }
        dot0s[qrt] = a0; dot0s[qrt + 1] = a1;
    }

    // ---- prologue: stage this unit's chunk 0 into buffer 0 ----
    float mv_cur = mrow[(u * NCH2) * 64];
    bool  val_cur = mv_cur > -0.5f;
    if (val_cur) {
        const int t0 = arow[(u * NCH2) * 64];
        const float* kp = &kh[(h * SQ + t0 + c) * DHD];
        const float* vp = &vh[(h * SQ + t0 + c) * DHD];
        float4 ka = *(const float4*)&kp[d4a];
        float4 kb = *(const float4*)&kp[d4b];
        Ks[u][0][d4a+0][c] = ka.x; Ks[u][0][d4a+1][c] = ka.y;
        Ks[u][0][d4a+2][c] = ka.z; Ks[u][0][d4a+3][c] = ka.w;
        Ks[u][0][d4b+0][c] = kb.x; Ks[u][0][d4b+1][c] = kb.y;
        Ks[u][0][d4b+2][c] = kb.z; Ks[u][0][d4b+3][c] = kb.w;
        *(float4*)&Vs[u][0][c][d4a] = *(const float4*)&vp[d4a];
        *(float4*)&Vs[u][0][c][d4b] = *(const float4*)&vp[d4b];
    }
    __syncthreads();

    // PV accumulators (c-slice partials, live across all chunks)
    float4 acc0a = make_float4(0.f,0.f,0.f,0.f), acc0b = acc0a;
    float4 acc1a = acc0a, acc1b = acc0a;
    float rps0 = 0.f, rps1 = 0.f;     // exp-sums for rows qrt, qrt+1 (qct slice)
    int cur = 0;

    for (int ci = 0; ci < NCH2; ++ci) {
        const int m0 = (u * NCH2 + ci) * 64;

        // issue next chunk's global loads early (latency hides under QK)
        bool  val_nxt = false;
        float mv_nxt  = 0.f;
        float4 ka, kb, va, vb;
        if (ci + 1 < NCH2) {
            mv_nxt  = mrow[m0 + 64];
            val_nxt = mv_nxt > -0.5f;
            if (val_nxt) {
                const int t0 = arow[m0 + 64];
                const float* kp = &kh[(h * SQ + t0 + c) * DHD];
                const float* vp = &vh[(h * SQ + t0 + c) * DHD];
                ka = *(const float4*)&kp[d4a];
                kb = *(const float4*)&kp[d4b];
                va = *(const float4*)&vp[d4a];
                vb = *(const float4*)&vp[d4b];
            }
        }

        // QK^T + scores + exp->Ps (K from LDS, Q from registers)
        if (val_cur) {
            const float* Kb = &Ks[u][cur][0][qct];
            float sc[2][4] = {};
            #pragma unroll
            for (int kk = 0; kk < 32; ++kk) {
                float4 b4 = *(const float4*)&Kb[kk * 68];
                sc[0][0] = fmaf(qr0[kk], b4.x, sc[0][0]);
                sc[0][1] = fmaf(qr0[kk], b4.y, sc[0][1]);
                sc[0][2] = fmaf(qr0[kk], b4.z, sc[0][2]);
                sc[0][3] = fmaf(qr0[kk], b4.w, sc[0][3]);
                sc[1][0] = fmaf(qr1[kk], b4.x, sc[1][0]);
                sc[1][1] = fmaf(qr1[kk], b4.y, sc[1][1]);
                sc[1][2] = fmaf(qr1[kk], b4.z, sc[1][2]);
                sc[1][3] = fmaf(qr1[kk], b4.w, sc[1][3]);
            }
            {
                *(float4*)&srow[(qrt + 0) * M + m0 + qct] =
                    make_float4(sc[0][0], sc[0][1], sc[0][2], sc[0][3]);
                float4 e;
                e.x = __expf(sc[0][0] - PSHIFT); e.y = __expf(sc[0][1] - PSHIFT);
                e.z = __expf(sc[0][2] - PSHIFT); e.w = __expf(sc[0][3] - PSHIFT);
                *(float4*)&Ps[u][qrt + 0][qct] = e;
                rps0 += (e.x + e.y) + (e.z + e.w);
            }
            {
                *(float4*)&srow[(qrt + 1) * M + m0 + qct] =
                    make_float4(sc[1][0], sc[1][1], sc[1][2], sc[1][3]);
                float4 e;
                e.x = __expf(sc[1][0] - PSHIFT); e.y = __expf(sc[1][1] - PSHIFT);
                e.z = __expf(sc[1][2] - PSHIFT); e.w = __expf(sc[1][3] - PSHIFT);
                *(float4*)&Ps[u][qrt + 1][qct] = e;
                rps1 += (e.x + e.y) + (e.z + e.w);
            }
        } else {
            #pragma unroll
            for (int i = 0; i < 8; ++i) {
                const int e = utid + i * 256;
                const int r = e >> 6, cc = e & 63;
                srow[r * M + m0 + cc] = dot0s[r] + mv_cur;
            }
        }

        // write prefetched chunk into the other buffer
        if (val_nxt) {
            Ks[u][cur^1][d4a+0][c] = ka.x; Ks[u][cur^1][d4a+1][c] = ka.y;
            Ks[u][cur^1][d4a+2][c] = ka.z; Ks[u][cur^1][d4a+3][c] = ka.w;
            Ks[u][cur^1][d4b+0][c] = kb.x; Ks[u][cur^1][d4b+1][c] = kb.y;
            Ks[u][cur^1][d4b+2][c] = kb.z; Ks[u][cur^1][d4b+3][c] = kb.w;
            *(float4*)&Vs[u][cur^1][c][d4a] = va;
            *(float4*)&Vs[u][cur^1][c][d4b] = vb;
        }
        __syncthreads();   // Ps visible + next buffer staged

        // PV accumulate: rows 2rp,2rp+1; dims dg*8..+7; c's cg*16..+15
        if (val_cur) {
            const float (*Vb)[36] = Vs[u][cur];
            const float* Pr0 = &Ps[u][2 * rp][0];
            const float* Pr1 = &Ps[u][2 * rp + 1][0];
            const int c0 = cg * 16;
            const int dd = dg * 8;
            #pragma unroll
            for (int k = 0; k < 4; ++k) {
                float4 pa = *(const float4*)&Pr0[c0 + k * 4];
                float4 pb = *(const float4*)&Pr1[c0 + k * 4];
                const float pav[4] = {pa.x, pa.y, pa.z, pa.w};
                const float pbv[4] = {pb.x, pb.y, pb.z, pb.w};
                #pragma unroll
                for (int t = 0; t < 4; ++t) {
                    const int cc2 = c0 + k * 4 + t;
                    float4 v0 = *(const float4*)&Vb[cc2][dd];
                    float4 v1 = *(const float4*)&Vb[cc2][dd + 4];
                    acc0a.x = fmaf(pav[t], v0.x, acc0a.x);
                    acc0a.y = fmaf(pav[t], v0.y, acc0a.y);
                    acc0a.z = fmaf(pav[t], v0.z, acc0a.z);
                    acc0a.w = fmaf(pav[t], v0.w, acc0a.w);
                    acc0b.x = fmaf(pav[t], v1.x, acc0b.x);
                    acc0b.y = fmaf(pav[t], v1.y, acc0b.y);
                    acc0b.z = fmaf(pav[t], v1.z, acc0b.z);
                    acc0b.w = fmaf(pav[t], v1.w, acc0b.w);
                    acc1a.x = fmaf(pbv[t], v0.x, acc1a.x);
                    acc1a.y = fmaf(pbv[t], v0.y, acc1a.y);
                    acc1a.z = fmaf(pbv[t], v0.z, acc1a.z);
                    acc1a.w = fmaf(pbv[t], v0.w, acc1a.w);
                    acc1b.x = fmaf(pbv[t], v1.x, acc1b.x);
                    acc1b.y = fmaf(pbv[t], v1.y, acc1b.y);
                    acc1b.z = fmaf(pbv[t], v1.z, acc1b.z);
                    acc1b.w = fmaf(pbv[t], v1.w, acc1b.w);
                }
            }
        }
        __syncthreads();   // Ps / Vs[cur] consumed; next iter may overwrite

        val_cur = val_nxt; mv_cur = mv_nxt; cur ^= 1;
    }

    // ---- epilogue: reduce 8 slabs (2 units x 4 c-groups) + 32 rps slices ----
    float* vacc = &Vs[0][0][0][0];              // vacc[8][32][36] overlay (fits)
    float* rsum = &Ps[0][0][0];                 // rsum[32][32] overlay
    {
        const int s = u * 4 + cg;
        float* base = vacc + (s * 32 + 2 * rp) * 36 + dg * 8;
        *(float4*)&base[0]  = acc0a; *(float4*)&base[4]  = acc0b;
        *(float4*)&base[36] = acc1a; *(float4*)&base[40] = acc1b;
        const int qg = utid >> 4;               // 0..15
        rsum[(u * 16 + qg) * 32 + qrt]     = rps0;
        rsum[(u * 16 + qg) * 32 + qrt + 1] = rps1;
    }
    __syncthreads();

    if (tid < 32) {
        float pt = 0.f;
        #pragma unroll
        for (int s2 = 0; s2 < 32; ++s2) pt += rsum[s2 * 32 + tid];
        invL[tid] = 1.0f / pt;
    }
    __syncthreads();

    float* ctxn = &Ks[0][0][0][0];              // ctxn[32][36] overlay
    if (tid < 256) {
        const int r = tid & 31, dq = tid >> 5;  // 8 dim-quads
        float4 sum = make_float4(0.f, 0.f, 0.f, 0.f);
        #pragma unroll
        for (int s = 0; s < 8; ++s) {
            float4 v = *(const float4*)&vacc[(s * 32 + r) * 36 + dq * 4];
            sum.x += v.x; sum.y += v.y; sum.z += v.z; sum.w += v.w;
        }
        const float il = invL[r];
        sum.x *= il; sum.y *= il; sum.z *= il; sum.w *= il;
        *(float4*)&ctxn[r * 36 + dq * 4] = sum;
    }
    __syncthreads();

    // ---- per-head outproj partial, atomically accumulated into out ----
    {
        const int jc = tid & 255, rg = tid >> 8;
        float wo[32];
        #pragma unroll
        for (int k = 0; k < 32; ++k)
            wo[k] = Wo[(h * DHD + k) * DMODEL + jc];
        for (int rr = rg * 16; rr < rg * 16 + 16; ++rr) {
            float a = 0.f;
            #pragma unroll
            for (int k4 = 0; k4 < 8; ++k4) {
                float4 cv = *(const float4*)&ctxn[rr * 36 + k4 * 4];
                a = fmaf(cv.x, wo[k4 * 4 + 0], a);
                a = fmaf(cv.y, wo[k4 * 4 + 1], a);
                a = fmaf(cv.z, wo[k4 * 4 + 2], a);
                a = fmaf(cv.w, wo[k4 * 4 + 3], a);
            }
            atomicAdd(&out[(s0 + rr) * DMODEL + jc], a);
        }
    }
}

extern "C" void kernel_launch(void* const* d_in, const int* in_sizes, int n_in,
                              void* d_out, int out_size, void* d_ws, size_t ws_size,
                              hipStream_t stream)
{
    const float* query  = (const float*)d_in[0];
    const float* value  = (const float*)d_in[1];
    const float* key_in = (const float*)d_in[2];
    const float* Wq = (const float*)d_in[3];
    const float* bq = (const float*)d_in[4];
    const float* Wk = (const float*)d_in[5];
    const float* bk = (const float*)d_in[6];
    const float* Wv = (const float*)d_in[7];
    const float* bv = (const float*)d_in[8];
    const float* Wo = (const float*)d_in[9];
    const float* bo = (const float*)d_in[10];
    const int*   aidx = (const int*)d_in[11];
    const float* mask = (const float*)d_in[12];

    const int M = in_sizes[11] / SQ;   // 768

    float* out        = (float*)d_out;
    float* scores_out = out + SQ * DMODEL;
    float* idx_out    = scores_out + NH * SQ * M;

    float* ws  = (float*)d_ws;
    float* qhp = ws;
    float* khp = qhp + NH * SQ * DHD;
    float* vhp = khp + NH * SQ * DHD;

    proj3<<<dim3(192, 3), 256, 0, stream>>>(
        query, value, key_in, Wq, bq, Wk, bk, Wv, bv,
        bo, out, aidx, idx_out, qhp, khp, vhp);

    attn2<<<dim3(NB, 2, NH), 512, 0, stream>>>(
        qhp, khp, vhp, aidx, mask, Wo, scores_out, out, M);
}

// Round 12
// 51.396 us; speedup vs baseline: 1.3621x; 1.0190x over previous
//
#include <hip/hip_runtime.h>
#include <math.h>

#define SQ 768
#define DMODEL 256
#define NH 8
#define DHD 32
#define NB 12                       // query blocks (SQ/64)
#define QSCALE 0.1767766952966369f  // 32^-0.5
#define PSHIFT 8.0f                 // fixed softmax shift (math-equiv to max-sub)

// ---------------------------------------------------------------------------
// Ledger (R5 algebra, repeatedly cross-checked): F=5.8us.
// proj3: v0 25 / v2 43 / v3 23 / v5 30 / v6 20 / v7 23.4 -> v6 is the floor
// of this family (W LDS dbuf, 8 rows, 96x3). attn2: v2 26.8 / v3 23.2 /
// v4 44(spill) / v5 31(Ps conflicts) -> v3 best. Best total = R7 = 49.0.
//
// Node 1 (v6, byte-identical to R7): W staged through LDS, 8 dbuf chunks.
// ---------------------------------------------------------------------------
__global__ __launch_bounds__(256) void proj3(
    const float* __restrict__ query, const float* __restrict__ value,
    const float* __restrict__ key_in,
    const float* __restrict__ Wq, const float* __restrict__ bq,
    const float* __restrict__ Wk, const float* __restrict__ bk,
    const float* __restrict__ Wv, const float* __restrict__ bv,
    const float* __restrict__ bo, float* __restrict__ outbuf,
    const int* __restrict__ aidx, float* __restrict__ idx_out,
    float* __restrict__ qhp, float* __restrict__ khp, float* __restrict__ vhp)
{
    const int j = threadIdx.x;

    // idx -> float copy: 288 blocks * 256 threads * 8 elems == 589824 exactly
    {
        const int bidf = blockIdx.y * 96 + blockIdx.x;
        const int i0 = (bidf * 256 + j) * 8;
        int4 a = *(const int4*)&aidx[i0];
        int4 b = *(const int4*)&aidx[i0 + 4];
        *(float4*)&idx_out[i0] =
            make_float4((float)a.x, (float)a.y, (float)a.z, (float)a.w);
        *(float4*)&idx_out[i0 + 4] =
            make_float4((float)b.x, (float)b.y, (float)b.z, (float)b.w);
    }

    const int s0 = blockIdx.x * 8;
    const int w  = blockIdx.y;

    if (w == 0) {   // init out rows with bias (node-2 atomically accumulates)
        const float bb = bo[j];
        #pragma unroll
        for (int r = 0; r < 8; ++r)
            outbuf[(s0 + r) * DMODEL + j] = bb;
    }

    const float *X, *W, *bias; float* outp; float scale;
    if (w == 0)      { X = query;  W = Wq; bias = bq; outp = qhp; scale = QSCALE; }
    else if (w == 1) { X = key_in; W = Wk; bias = bk; outp = khp; scale = 1.0f; }
    else             { X = value;  W = Wv; bias = bv; outp = vhp; scale = 1.0f; }

    __shared__ __align__(16) float xs[8][DMODEL];     // 8KB
    __shared__ __align__(16) float ws[2][32 * DMODEL]; // 64KB (dbuf, 32k x 256c)

    {
        float* xsf = &xs[0][0];
        const float* Xp = X + s0 * DMODEL;
        const int i0 = j * 8;
        *(float4*)&xsf[i0]     = *(const float4*)&Xp[i0];
        *(float4*)&xsf[i0 + 4] = *(const float4*)&Xp[i0 + 4];

        #pragma unroll
        for (int t = 0; t < 8; ++t)
            *(float4*)&ws[0][t * 1024 + j * 4] =
                *(const float4*)&W[t * 1024 + j * 4];
    }
    __syncthreads();

    const int j0 = (j & 63) * 4;        // 4 consecutive output cols
    const int r0 = (j >> 6) * 2;        // 2 rows (wave-uniform -> broadcast)

    float4 acc0 = make_float4(0.f, 0.f, 0.f, 0.f);
    float4 acc1 = make_float4(0.f, 0.f, 0.f, 0.f);
    int cur = 0;

    for (int c = 0; c < 8; ++c) {
        float4 wreg[8];
        if (c < 7) {
            const float* Wc = W + (c + 1) * 8192;
            #pragma unroll
            for (int t = 0; t < 8; ++t)
                wreg[t] = *(const float4*)&Wc[t * 1024 + j * 4];
        }

        const float* wb = &ws[cur][0];
        #pragma unroll
        for (int k4 = 0; k4 < 8; ++k4) {
            const int kb = c * 32 + k4 * 4;
            float4 x0 = *(const float4*)&xs[r0 + 0][kb];
            float4 x1 = *(const float4*)&xs[r0 + 1][kb];
            float4 w0 = *(const float4*)&wb[(k4 * 4 + 0) * DMODEL + j0];
            float4 w1 = *(const float4*)&wb[(k4 * 4 + 1) * DMODEL + j0];
            float4 w2 = *(const float4*)&wb[(k4 * 4 + 2) * DMODEL + j0];
            float4 w3 = *(const float4*)&wb[(k4 * 4 + 3) * DMODEL + j0];
            acc0.x = fmaf(x0.x, w0.x, acc0.x); acc0.y = fmaf(x0.x, w0.y, acc0.y);
            acc0.z = fmaf(x0.x, w0.z, acc0.z); acc0.w = fmaf(x0.x, w0.w, acc0.w);
            acc0.x = fmaf(x0.y, w1.x, acc0.x); acc0.y = fmaf(x0.y, w1.y, acc0.y);
            acc0.z = fmaf(x0.y, w1.z, acc0.z); acc0.w = fmaf(x0.y, w1.w, acc0.w);
            acc0.x = fmaf(x0.z, w2.x, acc0.x); acc0.y = fmaf(x0.z, w2.y, acc0.y);
            acc0.z = fmaf(x0.z, w2.z, acc0.z); acc0.w = fmaf(x0.z, w2.w, acc0.w);
            acc0.x = fmaf(x0.w, w3.x, acc0.x); acc0.y = fmaf(x0.w, w3.y, acc0.y);
            acc0.z = fmaf(x0.w, w3.z, acc0.z); acc0.w = fmaf(x0.w, w3.w, acc0.w);
            acc1.x = fmaf(x1.x, w0.x, acc1.x); acc1.y = fmaf(x1.x, w0.y, acc1.y);
            acc1.z = fmaf(x1.x, w0.z, acc1.z); acc1.w = fmaf(x1.x, w0.w, acc1.w);
            acc1.x = fmaf(x1.y, w1.x, acc1.x); acc1.y = fmaf(x1.y, w1.y, acc1.y);
            acc1.z = fmaf(x1.y, w1.z, acc1.z); acc1.w = fmaf(x1.y, w1.w, acc1.w);
            acc1.x = fmaf(x1.z, w2.x, acc1.x); acc1.y = fmaf(x1.z, w2.y, acc1.y);
            acc1.z = fmaf(x1.z, w2.z, acc1.z); acc1.w = fmaf(x1.z, w2.w, acc1.w);
            acc1.x = fmaf(x1.w, w3.x, acc1.x); acc1.y = fmaf(x1.w, w3.y, acc1.y);
            acc1.z = fmaf(x1.w, w3.z, acc1.z); acc1.w = fmaf(x1.w, w3.w, acc1.w);
        }

        if (c < 7) {
            float* wd = &ws[cur ^ 1][0];
            #pragma unroll
            for (int t = 0; t < 8; ++t)
                *(float4*)&wd[t * 1024 + j * 4] = wreg[t];
            __syncthreads();
            cur ^= 1;
        }
    }

    const float4 bb = *(const float4*)&bias[j0];
    const int h = j0 >> 5, d = j0 & 31;
    {
        float4 o0, o1;
        o0.x = (acc0.x + bb.x) * scale; o0.y = (acc0.y + bb.y) * scale;
        o0.z = (acc0.z + bb.z) * scale; o0.w = (acc0.w + bb.w) * scale;
        o1.x = (acc1.x + bb.x) * scale; o1.y = (acc1.y + bb.y) * scale;
        o1.z = (acc1.z + bb.z) * scale; o1.w = (acc1.w + bb.w) * scale;
        *(float4*)&outp[h * (SQ * DHD) + (s0 + r0 + 0) * DHD + d] = o0;
        *(float4*)&outp[h * (SQ * DHD) + (s0 + r0 + 1) * DHD + d] = o1;
    }
}

// ---------------------------------------------------------------------------
// Node 2 (v3k): v3 (23.2us) with ONE verified change — K staged ROW-MAJOR
// Kr[c][36] (2 b128 writes, like Vs) instead of transposed Ks[d][c]
// (8 scalar b32 writes). Saves ~22 cyc/chunk/wave of staging issue.
// QK reads become per-c dot products: Kr[qct+cq][d4] b128, 4 distinct
// addrs/wave (broadcast), 2-way bank alias (free, m136), same 32 reads,
// same FMA count, no new registers. Everything else byte-identical to v3.
// ---------------------------------------------------------------------------
__global__ __launch_bounds__(512) void attn2(
    const float* __restrict__ qh, const float* __restrict__ kh,
    const float* __restrict__ vh, const int* __restrict__ aidx,
    const float* __restrict__ mask, const float* __restrict__ Wo,
    float* __restrict__ scores_out, float* __restrict__ out, int M)
{
    __shared__ __align__(16) float Kr[2][2][64][36];   // [unit][buf][c][d]
    __shared__ __align__(16) float Vs[2][2][64][36];   // [unit][buf][c][d]
    __shared__ __align__(16) float Ps[2][32][68];      // [unit][row][c]
    __shared__ float dot0s[32];
    __shared__ float invL[32];

    const int b    = blockIdx.x;
    const int half = blockIdx.y;
    const int h    = blockIdx.z;
    const int s0b  = b * 64;
    const int s0   = s0b + half * 32;
    const int tid  = threadIdx.x;
    const int u    = tid >> 8;        // unit 0/1
    const int utid = tid & 255;
    const int NCH2 = M / 128;         // chunks per unit

    // QK mapping: 2 rows x 4 cols
    const int qrt = (utid & 15) * 2;  // rows (2)
    const int qct = (utid >> 4) * 4;  // cols (4)
    // PV mapping: same 2 rows; 8 dims; 16-c slice
    const int rp  = utid & 15;            // row pair (rows 2rp, 2rp+1 == qrt)
    const int dg  = (utid >> 4) & 3;      // dim group (8 dims)
    const int cg  = utid >> 6;            // c group (16 c's)
    // staging mapping
    const int c   = utid & 63;        // token within chunk
    const int sg  = utid >> 6;        // staging dim group 0..3
    const int d4a = sg * 4;
    const int d4b = 16 + sg * 4;

    const float* mrow = &mask[s0b * M];
    const int*   arow = &aidx[s0b * M];
    float*       srow = &scores_out[(h * SQ + s0) * M];

    // ---- Q rows (qrt, qrt+1) fully in registers ----
    float qr0[32], qr1[32];
    {
        const float* qp = &qh[(h * SQ + s0 + qrt) * DHD];
        #pragma unroll
        for (int d4 = 0; d4 < DHD; d4 += 4) {
            float4 a  = *(const float4*)&qp[d4];
            float4 b4 = *(const float4*)&qp[DHD + d4];
            qr0[d4] = a.x;  qr0[d4+1] = a.y;  qr0[d4+2] = a.z;  qr0[d4+3] = a.w;
            qr1[d4] = b4.x; qr1[d4+1] = b4.y; qr1[d4+2] = b4.z; qr1[d4+3] = b4.w;
        }
    }

    // dot0[r] = q_row . k[token 0]  (chunk-invariant; for padded chunks)
    if (tid < 16) {
        const float* k0 = &kh[h * SQ * DHD];
        float a0 = 0.f, a1 = 0.f;
        #pragma unroll
        for (int d = 0; d < DHD; ++d) {
            const float kv = k0[d];
            a0 = fmaf(qr0[d], kv, a0);
            a1 = fmaf(qr1[d], kv, a1);
        }
        dot0s[qrt] = a0; dot0s[qrt + 1] = a1;
    }

    // ---- prologue: stage this unit's chunk 0 into buffer 0 ----
    float mv_cur = mrow[(u * NCH2) * 64];
    bool  val_cur = mv_cur > -0.5f;
    if (val_cur) {
        const int t0 = arow[(u * NCH2) * 64];
        const float* kp = &kh[(h * SQ + t0 + c) * DHD];
        const float* vp = &vh[(h * SQ + t0 + c) * DHD];
        *(float4*)&Kr[u][0][c][d4a] = *(const float4*)&kp[d4a];
        *(float4*)&Kr[u][0][c][d4b] = *(const float4*)&kp[d4b];
        *(float4*)&Vs[u][0][c][d4a] = *(const float4*)&vp[d4a];
        *(float4*)&Vs[u][0][c][d4b] = *(const float4*)&vp[d4b];
    }
    __syncthreads();

    // PV accumulators (c-slice partials, live across all chunks)
    float4 acc0a = make_float4(0.f,0.f,0.f,0.f), acc0b = acc0a;
    float4 acc1a = acc0a, acc1b = acc0a;
    float rps0 = 0.f, rps1 = 0.f;     // exp-sums for rows qrt, qrt+1 (qct slice)
    int cur = 0;

    for (int ci = 0; ci < NCH2; ++ci) {
        const int m0 = (u * NCH2 + ci) * 64;

        // issue next chunk's global loads early (latency hides under QK)
        bool  val_nxt = false;
        float mv_nxt  = 0.f;
        float4 ka, kb, va, vb;
        if (ci + 1 < NCH2) {
            mv_nxt  = mrow[m0 + 64];
            val_nxt = mv_nxt > -0.5f;
            if (val_nxt) {
                const int t0 = arow[m0 + 64];
                const float* kp = &kh[(h * SQ + t0 + c) * DHD];
                const float* vp = &vh[(h * SQ + t0 + c) * DHD];
                ka = *(const float4*)&kp[d4a];
                kb = *(const float4*)&kp[d4b];
                va = *(const float4*)&vp[d4a];
                vb = *(const float4*)&vp[d4b];
            }
        }

        // QK^T + scores + exp->Ps (K row-major from LDS, Q from registers)
        if (val_cur) {
            const float (*Kb)[36] = Kr[u][cur];
            float sc[2][4] = {};
            #pragma unroll
            for (int d4 = 0; d4 < 32; d4 += 4) {
                float4 k0 = *(const float4*)&Kb[qct + 0][d4];
                float4 k1 = *(const float4*)&Kb[qct + 1][d4];
                float4 k2 = *(const float4*)&Kb[qct + 2][d4];
                float4 k3 = *(const float4*)&Kb[qct + 3][d4];
                sc[0][0] = fmaf(qr0[d4+0], k0.x, sc[0][0]);
                sc[0][0] = fmaf(qr0[d4+1], k0.y, sc[0][0]);
                sc[0][0] = fmaf(qr0[d4+2], k0.z, sc[0][0]);
                sc[0][0] = fmaf(qr0[d4+3], k0.w, sc[0][0]);
                sc[0][1] = fmaf(qr0[d4+0], k1.x, sc[0][1]);
                sc[0][1] = fmaf(qr0[d4+1], k1.y, sc[0][1]);
                sc[0][1] = fmaf(qr0[d4+2], k1.z, sc[0][1]);
                sc[0][1] = fmaf(qr0[d4+3], k1.w, sc[0][1]);
                sc[0][2] = fmaf(qr0[d4+0], k2.x, sc[0][2]);
                sc[0][2] = fmaf(qr0[d4+1], k2.y, sc[0][2]);
                sc[0][2] = fmaf(qr0[d4+2], k2.z, sc[0][2]);
                sc[0][2] = fmaf(qr0[d4+3], k2.w, sc[0][2]);
                sc[0][3] = fmaf(qr0[d4+0], k3.x, sc[0][3]);
                sc[0][3] = fmaf(qr0[d4+1], k3.y, sc[0][3]);
                sc[0][3] = fmaf(qr0[d4+2], k3.z, sc[0][3]);
                sc[0][3] = fmaf(qr0[d4+3], k3.w, sc[0][3]);
                sc[1][0] = fmaf(qr1[d4+0], k0.x, sc[1][0]);
                sc[1][0] = fmaf(qr1[d4+1], k0.y, sc[1][0]);
                sc[1][0] = fmaf(qr1[d4+2], k0.z, sc[1][0]);
                sc[1][0] = fmaf(qr1[d4+3], k0.w, sc[1][0]);
                sc[1][1] = fmaf(qr1[d4+0], k1.x, sc[1][1]);
                sc[1][1] = fmaf(qr1[d4+1], k1.y, sc[1][1]);
                sc[1][1] = fmaf(qr1[d4+2], k1.z, sc[1][1]);
                sc[1][1] = fmaf(qr1[d4+3], k1.w, sc[1][1]);
                sc[1][2] = fmaf(qr1[d4+0], k2.x, sc[1][2]);
                sc[1][2] = fmaf(qr1[d4+1], k2.y, sc[1][2]);
                sc[1][2] = fmaf(qr1[d4+2], k2.z, sc[1][2]);
                sc[1][2] = fmaf(qr1[d4+3], k2.w, sc[1][2]);
                sc[1][3] = fmaf(qr1[d4+0], k3.x, sc[1][3]);
                sc[1][3] = fmaf(qr1[d4+1], k3.y, sc[1][3]);
                sc[1][3] = fmaf(qr1[d4+2], k3.z, sc[1][3]);
                sc[1][3] = fmaf(qr1[d4+3], k3.w, sc[1][3]);
            }
            {
                *(float4*)&srow[(qrt + 0) * M + m0 + qct] =
                    make_float4(sc[0][0], sc[0][1], sc[0][2], sc[0][3]);
                float4 e;
                e.x = __expf(sc[0][0] - PSHIFT); e.y = __expf(sc[0][1] - PSHIFT);
                e.z = __expf(sc[0][2] - PSHIFT); e.w = __expf(sc[0][3] - PSHIFT);
                *(float4*)&Ps[u][qrt + 0][qct] = e;
                rps0 += (e.x + e.y) + (e.z + e.w);
            }
            {
                *(float4*)&srow[(qrt + 1) * M + m0 + qct] =
                    make_float4(sc[1][0], sc[1][1], sc[1][2], sc[1][3]);
                float4 e;
                e.x = __expf(sc[1][0] - PSHIFT); e.y = __expf(sc[1][1] - PSHIFT);
                e.z = __expf(sc[1][2] - PSHIFT); e.w = __expf(sc[1][3] - PSHIFT);
                *(float4*)&Ps[u][qrt + 1][qct] = e;
                rps1 += (e.x + e.y) + (e.z + e.w);
            }
        } else {
            #pragma unroll
            for (int i = 0; i < 8; ++i) {
                const int e = utid + i * 256;
                const int r = e >> 6, cc = e & 63;
                srow[r * M + m0 + cc] = dot0s[r] + mv_cur;
            }
        }

        // write prefetched chunk into the other buffer (row-major, 4 b128)
        if (val_nxt) {
            *(float4*)&Kr[u][cur^1][c][d4a] = ka;
            *(float4*)&Kr[u][cur^1][c][d4b] = kb;
            *(float4*)&Vs[u][cur^1][c][d4a] = va;
            *(float4*)&Vs[u][cur^1][c][d4b] = vb;
        }
        __syncthreads();   // Ps visible + next buffer staged

        // PV accumulate: rows 2rp,2rp+1; dims dg*8..+7; c's cg*16..+15
        if (val_cur) {
            const float (*Vb)[36] = Vs[u][cur];
            const float* Pr0 = &Ps[u][2 * rp][0];
            const float* Pr1 = &Ps[u][2 * rp + 1][0];
            const int c0 = cg * 16;
            const int dd = dg * 8;
            #pragma unroll
            for (int k = 0; k < 4; ++k) {
                float4 pa = *(const float4*)&Pr0[c0 + k * 4];
                float4 pb = *(const float4*)&Pr1[c0 + k * 4];
                const float pav[4] = {pa.x, pa.y, pa.z, pa.w};
                const float pbv[4] = {pb.x, pb.y, pb.z, pb.w};
                #pragma unroll
                for (int t = 0; t < 4; ++t) {
                    const int cc2 = c0 + k * 4 + t;
                    float4 v0 = *(const float4*)&Vb[cc2][dd];
                    float4 v1 = *(const float4*)&Vb[cc2][dd + 4];
                    acc0a.x = fmaf(pav[t], v0.x, acc0a.x);
                    acc0a.y = fmaf(pav[t], v0.y, acc0a.y);
                    acc0a.z = fmaf(pav[t], v0.z, acc0a.z);
                    acc0a.w = fmaf(pav[t], v0.w, acc0a.w);
                    acc0b.x = fmaf(pav[t], v1.x, acc0b.x);
                    acc0b.y = fmaf(pav[t], v1.y, acc0b.y);
                    acc0b.z = fmaf(pav[t], v1.z, acc0b.z);
                    acc0b.w = fmaf(pav[t], v1.w, acc0b.w);
                    acc1a.x = fmaf(pbv[t], v0.x, acc1a.x);
                    acc1a.y = fmaf(pbv[t], v0.y, acc1a.y);
                    acc1a.z = fmaf(pbv[t], v0.z, acc1a.z);
                    acc1a.w = fmaf(pbv[t], v0.w, acc1a.w);
                    acc1b.x = fmaf(pbv[t], v1.x, acc1b.x);
                    acc1b.y = fmaf(pbv[t], v1.y, acc1b.y);
                    acc1b.z = fmaf(pbv[t], v1.z, acc1b.z);
                    acc1b.w = fmaf(pbv[t], v1.w, acc1b.w);
                }
            }
        }
        __syncthreads();   // Ps / Vs[cur] consumed; next iter may overwrite

        val_cur = val_nxt; mv_cur = mv_nxt; cur ^= 1;
    }

    // ---- epilogue: reduce 8 slabs (2 units x 4 c-groups) + 32 rps slices ----
    float* vacc = &Vs[0][0][0][0];              // vacc[8][32][36] overlay (fits)
    float* rsum = &Ps[0][0][0];                 // rsum[32][32] overlay
    {
        const int s = u * 4 + cg;
        float* base = vacc + (s * 32 + 2 * rp) * 36 + dg * 8;
        *(float4*)&base[0]  = acc0a; *(float4*)&base[4]  = acc0b;
        *(float4*)&base[36] = acc1a; *(float4*)&base[40] = acc1b;
        const int qg = utid >> 4;               // 0..15
        rsum[(u * 16 + qg) * 32 + qrt]     = rps0;
        rsum[(u * 16 + qg) * 32 + qrt + 1] = rps1;
    }
    __syncthreads();

    if (tid < 32) {
        float pt = 0.f;
        #pragma unroll
        for (int s2 = 0; s2 < 32; ++s2) pt += rsum[s2 * 32 + tid];
        invL[tid] = 1.0f / pt;
    }
    __syncthreads();

    float* ctxn = &Kr[0][0][0][0];              // ctxn[32][36] overlay
    if (tid < 256) {
        const int r = tid & 31, dq = tid >> 5;  // 8 dim-quads
        float4 sum = make_float4(0.f, 0.f, 0.f, 0.f);
        #pragma unroll
        for (int s = 0; s < 8; ++s) {
            float4 v = *(const float4*)&vacc[(s * 32 + r) * 36 + dq * 4];
            sum.x += v.x; sum.y += v.y; sum.z += v.z; sum.w += v.w;
        }
        const float il = invL[r];
        sum.x *= il; sum.y *= il; sum.z *= il; sum.w *= il;
        *(float4*)&ctxn[r * 36 + dq * 4] = sum;
    }
    __syncthreads();

    // ---- per-head outproj partial, atomically accumulated into out ----
    {
        const int jc = tid & 255, rg = tid >> 8;
        float wo[32];
        #pragma unroll
        for (int k = 0; k < 32; ++k)
            wo[k] = Wo[(h * DHD + k) * DMODEL + jc];
        for (int rr = rg * 16; rr < rg * 16 + 16; ++rr) {
            float a = 0.f;
            #pragma unroll
            for (int k4 = 0; k4 < 8; ++k4) {
                float4 cv = *(const float4*)&ctxn[rr * 36 + k4 * 4];
                a = fmaf(cv.x, wo[k4 * 4 + 0], a);
                a = fmaf(cv.y, wo[k4 * 4 + 1], a);
                a = fmaf(cv.z, wo[k4 * 4 + 2], a);
                a = fmaf(cv.w, wo[k4 * 4 + 3], a);
            }
            atomicAdd(&out[(s0 + rr) * DMODEL + jc], a);
        }
    }
}

extern "C" void kernel_launch(void* const* d_in, const int* in_sizes, int n_in,
                              void* d_out, int out_size, void* d_ws, size_t ws_size,
                              hipStream_t stream)
{
    const float* query  = (const float*)d_in[0];
    const float* value  = (const float*)d_in[1];
    const float* key_in = (const float*)d_in[2];
    const float* Wq = (const float*)d_in[3];
    const float* bq = (const float*)d_in[4];
    const float* Wk = (const float*)d_in[5];
    const float* bk = (const float*)d_in[6];
    const float* Wv = (const float*)d_in[7];
    const float* bv = (const float*)d_in[8];
    const float* Wo = (const float*)d_in[9];
    const float* bo = (const float*)d_in[10];
    const int*   aidx = (const int*)d_in[11];
    const float* mask = (const float*)d_in[12];

    const int M = in_sizes[11] / SQ;   // 768

    float* out        = (float*)d_out;
    float* scores_out = out + SQ * DMODEL;
    float* idx_out    = scores_out + NH * SQ * M;

    float* ws  = (float*)d_ws;
    float* qhp = ws;
    float* khp = qhp + NH * SQ * DHD;
    float* vhp = khp + NH * SQ * DHD;

    proj3<<<dim3(96, 3), 256, 0, stream>>>(
        query, value, key_in, Wq, bq, Wk, bk, Wv, bv,
        bo, out, aidx, idx_out, qhp, khp, vhp);

    attn2<<<dim3(NB, 2, NH), 512, 0, stream>>>(
        qhp, khp, vhp, aidx, mask, Wo, scores_out, out, M);
}

// Round 13
// 48.800 us; speedup vs baseline: 1.4345x; 1.0532x over previous
//
#include <hip/hip_runtime.h>
#include <math.h>

#define SQ 768
#define DMODEL 256
#define NH 8
#define DHD 32
#define NB 12                       // query blocks (SQ/64)
#define QSCALE 0.1767766952966369f  // 32^-0.5
#define PSHIFT 8.0f                 // fixed softmax shift (math-equiv to max-sub)

// ---------------------------------------------------------------------------
// LOCK-IN ROUND: byte-exact revert to the R7 configuration — the session
// best (measured 48.96us). Ledger (R5 decomposition, F=5.8us):
//   proj3: v0 25 / v2 43 / v3 23 / v5 30 / v6 20 <- / v7 23.4
//   attn2: v2 26.8 / v3 23.2 <- / v4 44 (spill) / v5 31 (conflicts) / v3k 25.6
// All post-R7 single-variable changes regressed; grid-split analysis shows
// per-block LDS issue is thread-bound (K reads amortize over register-held
// rows), so finer grids cannot reduce total issue either.
//
// Node 1 (v6): W staged through LDS in 8 double-buffered 32-k chunks,
// reg-staged async-split. 8 rows/block, grid (96,3).
// ---------------------------------------------------------------------------
__global__ __launch_bounds__(256) void proj3(
    const float* __restrict__ query, const float* __restrict__ value,
    const float* __restrict__ key_in,
    const float* __restrict__ Wq, const float* __restrict__ bq,
    const float* __restrict__ Wk, const float* __restrict__ bk,
    const float* __restrict__ Wv, const float* __restrict__ bv,
    const float* __restrict__ bo, float* __restrict__ outbuf,
    const int* __restrict__ aidx, float* __restrict__ idx_out,
    float* __restrict__ qhp, float* __restrict__ khp, float* __restrict__ vhp)
{
    const int j = threadIdx.x;

    // idx -> float copy: 288 blocks * 256 threads * 8 elems == 589824 exactly
    {
        const int bidf = blockIdx.y * 96 + blockIdx.x;
        const int i0 = (bidf * 256 + j) * 8;
        int4 a = *(const int4*)&aidx[i0];
        int4 b = *(const int4*)&aidx[i0 + 4];
        *(float4*)&idx_out[i0] =
            make_float4((float)a.x, (float)a.y, (float)a.z, (float)a.w);
        *(float4*)&idx_out[i0 + 4] =
            make_float4((float)b.x, (float)b.y, (float)b.z, (float)b.w);
    }

    const int s0 = blockIdx.x * 8;
    const int w  = blockIdx.y;

    if (w == 0) {   // init out rows with bias (node-2 atomically accumulates)
        const float bb = bo[j];
        #pragma unroll
        for (int r = 0; r < 8; ++r)
            outbuf[(s0 + r) * DMODEL + j] = bb;
    }

    const float *X, *W, *bias; float* outp; float scale;
    if (w == 0)      { X = query;  W = Wq; bias = bq; outp = qhp; scale = QSCALE; }
    else if (w == 1) { X = key_in; W = Wk; bias = bk; outp = khp; scale = 1.0f; }
    else             { X = value;  W = Wv; bias = bv; outp = vhp; scale = 1.0f; }

    __shared__ __align__(16) float xs[8][DMODEL];     // 8KB
    __shared__ __align__(16) float ws[2][32 * DMODEL]; // 64KB (dbuf, 32k x 256c)

    // stage X (8 rows) + W chunk 0, then barrier
    {
        float* xsf = &xs[0][0];
        const float* Xp = X + s0 * DMODEL;
        const int i0 = j * 8;
        *(float4*)&xsf[i0]     = *(const float4*)&Xp[i0];
        *(float4*)&xsf[i0 + 4] = *(const float4*)&Xp[i0 + 4];

        #pragma unroll
        for (int t = 0; t < 8; ++t)
            *(float4*)&ws[0][t * 1024 + j * 4] =
                *(const float4*)&W[t * 1024 + j * 4];
    }
    __syncthreads();

    const int j0 = (j & 63) * 4;        // 4 consecutive output cols
    const int r0 = (j >> 6) * 2;        // 2 rows (wave-uniform -> broadcast)

    float4 acc0 = make_float4(0.f, 0.f, 0.f, 0.f);
    float4 acc1 = make_float4(0.f, 0.f, 0.f, 0.f);
    int cur = 0;

    for (int c = 0; c < 8; ++c) {
        // issue next chunk's global loads early (hide HBM latency under FMA)
        float4 wreg[8];
        if (c < 7) {
            const float* Wc = W + (c + 1) * 8192;
            #pragma unroll
            for (int t = 0; t < 8; ++t)
                wreg[t] = *(const float4*)&Wc[t * 1024 + j * 4];
        }

        // compute chunk c from LDS
        const float* wb = &ws[cur][0];
        #pragma unroll
        for (int k4 = 0; k4 < 8; ++k4) {
            const int kb = c * 32 + k4 * 4;
            float4 x0 = *(const float4*)&xs[r0 + 0][kb];
            float4 x1 = *(const float4*)&xs[r0 + 1][kb];
            float4 w0 = *(const float4*)&wb[(k4 * 4 + 0) * DMODEL + j0];
            float4 w1 = *(const float4*)&wb[(k4 * 4 + 1) * DMODEL + j0];
            float4 w2 = *(const float4*)&wb[(k4 * 4 + 2) * DMODEL + j0];
            float4 w3 = *(const float4*)&wb[(k4 * 4 + 3) * DMODEL + j0];
            acc0.x = fmaf(x0.x, w0.x, acc0.x); acc0.y = fmaf(x0.x, w0.y, acc0.y);
            acc0.z = fmaf(x0.x, w0.z, acc0.z); acc0.w = fmaf(x0.x, w0.w, acc0.w);
            acc0.x = fmaf(x0.y, w1.x, acc0.x); acc0.y = fmaf(x0.y, w1.y, acc0.y);
            acc0.z = fmaf(x0.y, w1.z, acc0.z); acc0.w = fmaf(x0.y, w1.w, acc0.w);
            acc0.x = fmaf(x0.z, w2.x, acc0.x); acc0.y = fmaf(x0.z, w2.y, acc0.y);
            acc0.z = fmaf(x0.z, w2.z, acc0.z); acc0.w = fmaf(x0.z, w2.w, acc0.w);
            acc0.x = fmaf(x0.w, w3.x, acc0.x); acc0.y = fmaf(x0.w, w3.y, acc0.y);
            acc0.z = fmaf(x0.w, w3.z, acc0.z); acc0.w = fmaf(x0.w, w3.w, acc0.w);
            acc1.x = fmaf(x1.x, w0.x, acc1.x); acc1.y = fmaf(x1.x, w0.y, acc1.y);
            acc1.z = fmaf(x1.x, w0.z, acc1.z); acc1.w = fmaf(x1.x, w0.w, acc1.w);
            acc1.x = fmaf(x1.y, w1.x, acc1.x); acc1.y = fmaf(x1.y, w1.y, acc1.y);
            acc1.z = fmaf(x1.y, w1.z, acc1.z); acc1.w = fmaf(x1.y, w1.w, acc1.w);
            acc1.x = fmaf(x1.z, w2.x, acc1.x); acc1.y = fmaf(x1.z, w2.y, acc1.y);
            acc1.z = fmaf(x1.z, w2.z, acc1.z); acc1.w = fmaf(x1.z, w2.w, acc1.w);
            acc1.x = fmaf(x1.w, w3.x, acc1.x); acc1.y = fmaf(x1.w, w3.y, acc1.y);
            acc1.z = fmaf(x1.w, w3.z, acc1.z); acc1.w = fmaf(x1.w, w3.w, acc1.w);
        }

        // write prefetched chunk into the other buffer, one barrier per chunk
        if (c < 7) {
            float* wd = &ws[cur ^ 1][0];
            #pragma unroll
            for (int t = 0; t < 8; ++t)
                *(float4*)&wd[t * 1024 + j * 4] = wreg[t];
            __syncthreads();
            cur ^= 1;
        }
    }

    const float4 bb = *(const float4*)&bias[j0];
    const int h = j0 >> 5, d = j0 & 31;
    {
        float4 o0, o1;
        o0.x = (acc0.x + bb.x) * scale; o0.y = (acc0.y + bb.y) * scale;
        o0.z = (acc0.z + bb.z) * scale; o0.w = (acc0.w + bb.w) * scale;
        o1.x = (acc1.x + bb.x) * scale; o1.y = (acc1.y + bb.y) * scale;
        o1.z = (acc1.z + bb.z) * scale; o1.w = (acc1.w + bb.w) * scale;
        *(float4*)&outp[h * (SQ * DHD) + (s0 + r0 + 0) * DHD + d] = o0;
        *(float4*)&outp[h * (SQ * DHD) + (s0 + r0 + 1) * DHD + d] = o1;
    }
}

// ---------------------------------------------------------------------------
// Node 2 (v3, byte-exact: measured 23.2us, matches its LDS-issue model):
// Ps transposed [row][c]; PV register tile 2r x 8d x 16c; rps in-register
// during QK; 8-slab LDS reduce epilogue.
// ---------------------------------------------------------------------------
__global__ __launch_bounds__(512) void attn2(
    const float* __restrict__ qh, const float* __restrict__ kh,
    const float* __restrict__ vh, const int* __restrict__ aidx,
    const float* __restrict__ mask, const float* __restrict__ Wo,
    float* __restrict__ scores_out, float* __restrict__ out, int M)
{
    __shared__ __align__(16) float Ks[2][2][32][68];   // [unit][buf][d][c]
    __shared__ __align__(16) float Vs[2][2][64][36];   // [unit][buf][c][d]
    __shared__ __align__(16) float Ps[2][32][68];      // [unit][row][c]
    __shared__ float dot0s[32];
    __shared__ float invL[32];

    const int b    = blockIdx.x;
    const int half = blockIdx.y;
    const int h    = blockIdx.z;
    const int s0b  = b * 64;
    const int s0   = s0b + half * 32;
    const int tid  = threadIdx.x;
    const int u    = tid >> 8;        // unit 0/1
    const int utid = tid & 255;
    const int NCH2 = M / 128;         // chunks per unit

    // QK mapping: 2 rows x 4 cols
    const int qrt = (utid & 15) * 2;  // rows (2)
    const int qct = (utid >> 4) * 4;  // cols (4)
    // PV mapping: same 2 rows; 8 dims; 16-c slice
    const int rp  = utid & 15;            // row pair (rows 2rp, 2rp+1 == qrt)
    const int dg  = (utid >> 4) & 3;      // dim group (8 dims)
    const int cg  = utid >> 6;            // c group (16 c's)
    // staging mapping
    const int c   = utid & 63;        // token within chunk
    const int sg  = utid >> 6;        // staging dim group 0..3
    const int d4a = sg * 4;
    const int d4b = 16 + sg * 4;

    const float* mrow = &mask[s0b * M];
    const int*   arow = &aidx[s0b * M];
    float*       srow = &scores_out[(h * SQ + s0) * M];

    // ---- Q rows (qrt, qrt+1) fully in registers ----
    float qr0[32], qr1[32];
    {
        const float* qp = &qh[(h * SQ + s0 + qrt) * DHD];
        #pragma unroll
        for (int d4 = 0; d4 < DHD; d4 += 4) {
            float4 a  = *(const float4*)&qp[d4];
            float4 b4 = *(const float4*)&qp[DHD + d4];
            qr0[d4] = a.x;  qr0[d4+1] = a.y;  qr0[d4+2] = a.z;  qr0[d4+3] = a.w;
            qr1[d4] = b4.x; qr1[d4+1] = b4.y; qr1[d4+2] = b4.z; qr1[d4+3] = b4.w;
        }
    }

    // dot0[r] = q_row . k[token 0]  (chunk-invariant; for padded chunks)
    if (tid < 16) {
        const float* k0 = &kh[h * SQ * DHD];
        float a0 = 0.f, a1 = 0.f;
        #pragma unroll
        for (int d = 0; d < DHD; ++d) {
            const float kv = k0[d];
            a0 = fmaf(qr0[d], kv, a0);
            a1 = fmaf(qr1[d], kv, a1);
        }
        dot0s[qrt] = a0; dot0s[qrt + 1] = a1;
    }

    // ---- prologue: stage this unit's chunk 0 into buffer 0 ----
    float mv_cur = mrow[(u * NCH2) * 64];
    bool  val_cur = mv_cur > -0.5f;
    if (val_cur) {
        const int t0 = arow[(u * NCH2) * 64];
        const float* kp = &kh[(h * SQ + t0 + c) * DHD];
        const float* vp = &vh[(h * SQ + t0 + c) * DHD];
        float4 ka = *(const float4*)&kp[d4a];
        float4 kb = *(const float4*)&kp[d4b];
        Ks[u][0][d4a+0][c] = ka.x; Ks[u][0][d4a+1][c] = ka.y;
        Ks[u][0][d4a+2][c] = ka.z; Ks[u][0][d4a+3][c] = ka.w;
        Ks[u][0][d4b+0][c] = kb.x; Ks[u][0][d4b+1][c] = kb.y;
        Ks[u][0][d4b+2][c] = kb.z; Ks[u][0][d4b+3][c] = kb.w;
        *(float4*)&Vs[u][0][c][d4a] = *(const float4*)&vp[d4a];
        *(float4*)&Vs[u][0][c][d4b] = *(const float4*)&vp[d4b];
    }
    __syncthreads();

    // PV accumulators (c-slice partials, live across all chunks)
    float4 acc0a = make_float4(0.f,0.f,0.f,0.f), acc0b = acc0a;
    float4 acc1a = acc0a, acc1b = acc0a;
    float rps0 = 0.f, rps1 = 0.f;     // exp-sums for rows qrt, qrt+1 (qct slice)
    int cur = 0;

    for (int ci = 0; ci < NCH2; ++ci) {
        const int m0 = (u * NCH2 + ci) * 64;

        // issue next chunk's global loads early (latency hides under QK)
        bool  val_nxt = false;
        float mv_nxt  = 0.f;
        float4 ka, kb, va, vb;
        if (ci + 1 < NCH2) {
            mv_nxt  = mrow[m0 + 64];
            val_nxt = mv_nxt > -0.5f;
            if (val_nxt) {
                const int t0 = arow[m0 + 64];
                const float* kp = &kh[(h * SQ + t0 + c) * DHD];
                const float* vp = &vh[(h * SQ + t0 + c) * DHD];
                ka = *(const float4*)&kp[d4a];
                kb = *(const float4*)&kp[d4b];
                va = *(const float4*)&vp[d4a];
                vb = *(const float4*)&vp[d4b];
            }
        }

        // QK^T + scores + exp->Ps (K from LDS, Q from registers)
        if (val_cur) {
            const float* Kb = &Ks[u][cur][0][qct];
            float sc[2][4] = {};
            #pragma unroll
            for (int kk = 0; kk < 32; ++kk) {
                float4 b4 = *(const float4*)&Kb[kk * 68];
                sc[0][0] = fmaf(qr0[kk], b4.x, sc[0][0]);
                sc[0][1] = fmaf(qr0[kk], b4.y, sc[0][1]);
                sc[0][2] = fmaf(qr0[kk], b4.z, sc[0][2]);
                sc[0][3] = fmaf(qr0[kk], b4.w, sc[0][3]);
                sc[1][0] = fmaf(qr1[kk], b4.x, sc[1][0]);
                sc[1][1] = fmaf(qr1[kk], b4.y, sc[1][1]);
                sc[1][2] = fmaf(qr1[kk], b4.z, sc[1][2]);
                sc[1][3] = fmaf(qr1[kk], b4.w, sc[1][3]);
            }
            {
                *(float4*)&srow[(qrt + 0) * M + m0 + qct] =
                    make_float4(sc[0][0], sc[0][1], sc[0][2], sc[0][3]);
                float4 e;
                e.x = __expf(sc[0][0] - PSHIFT); e.y = __expf(sc[0][1] - PSHIFT);
                e.z = __expf(sc[0][2] - PSHIFT); e.w = __expf(sc[0][3] - PSHIFT);
                *(float4*)&Ps[u][qrt + 0][qct] = e;
                rps0 += (e.x + e.y) + (e.z + e.w);
            }
            {
                *(float4*)&srow[(qrt + 1) * M + m0 + qct] =
                    make_float4(sc[1][0], sc[1][1], sc[1][2], sc[1][3]);
                float4 e;
                e.x = __expf(sc[1][0] - PSHIFT); e.y = __expf(sc[1][1] - PSHIFT);
                e.z = __expf(sc[1][2] - PSHIFT); e.w = __expf(sc[1][3] - PSHIFT);
                *(float4*)&Ps[u][qrt + 1][qct] = e;
                rps1 += (e.x + e.y) + (e.z + e.w);
            }
        } else {
            #pragma unroll
            for (int i = 0; i < 8; ++i) {
                const int e = utid + i * 256;
                const int r = e >> 6, cc = e & 63;
                srow[r * M + m0 + cc] = dot0s[r] + mv_cur;
            }
        }

        // write prefetched chunk into the other buffer
        if (val_nxt) {
            Ks[u][cur^1][d4a+0][c] = ka.x; Ks[u][cur^1][d4a+1][c] = ka.y;
            Ks[u][cur^1][d4a+2][c] = ka.z; Ks[u][cur^1][d4a+3][c] = ka.w;
            Ks[u][cur^1][d4b+0][c] = kb.x; Ks[u][cur^1][d4b+1][c] = kb.y;
            Ks[u][cur^1][d4b+2][c] = kb.z; Ks[u][cur^1][d4b+3][c] = kb.w;
            *(float4*)&Vs[u][cur^1][c][d4a] = va;
            *(float4*)&Vs[u][cur^1][c][d4b] = vb;
        }
        __syncthreads();   // Ps visible + next buffer staged

        // PV accumulate: rows 2rp,2rp+1; dims dg*8..+7; c's cg*16..+15
        if (val_cur) {
            const float (*Vb)[36] = Vs[u][cur];
            const float* Pr0 = &Ps[u][2 * rp][0];
            const float* Pr1 = &Ps[u][2 * rp + 1][0];
            const int c0 = cg * 16;
            const int dd = dg * 8;
            #pragma unroll
            for (int k = 0; k < 4; ++k) {
                float4 pa = *(const float4*)&Pr0[c0 + k * 4];
                float4 pb = *(const float4*)&Pr1[c0 + k * 4];
                const float pav[4] = {pa.x, pa.y, pa.z, pa.w};
                const float pbv[4] = {pb.x, pb.y, pb.z, pb.w};
                #pragma unroll
                for (int t = 0; t < 4; ++t) {
                    const int cc2 = c0 + k * 4 + t;
                    float4 v0 = *(const float4*)&Vb[cc2][dd];
                    float4 v1 = *(const float4*)&Vb[cc2][dd + 4];
                    acc0a.x = fmaf(pav[t], v0.x, acc0a.x);
                    acc0a.y = fmaf(pav[t], v0.y, acc0a.y);
                    acc0a.z = fmaf(pav[t], v0.z, acc0a.z);
                    acc0a.w = fmaf(pav[t], v0.w, acc0a.w);
                    acc0b.x = fmaf(pav[t], v1.x, acc0b.x);
                    acc0b.y = fmaf(pav[t], v1.y, acc0b.y);
                    acc0b.z = fmaf(pav[t], v1.z, acc0b.z);
                    acc0b.w = fmaf(pav[t], v1.w, acc0b.w);
                    acc1a.x = fmaf(pbv[t], v0.x, acc1a.x);
                    acc1a.y = fmaf(pbv[t], v0.y, acc1a.y);
                    acc1a.z = fmaf(pbv[t], v0.z, acc1a.z);
                    acc1a.w = fmaf(pbv[t], v0.w, acc1a.w);
                    acc1b.x = fmaf(pbv[t], v1.x, acc1b.x);
                    acc1b.y = fmaf(pbv[t], v1.y, acc1b.y);
                    acc1b.z = fmaf(pbv[t], v1.z, acc1b.z);
                    acc1b.w = fmaf(pbv[t], v1.w, acc1b.w);
                }
            }
        }
        __syncthreads();   // Ps / Vs[cur] consumed; next iter may overwrite

        val_cur = val_nxt; mv_cur = mv_nxt; cur ^= 1;
    }

    // ---- epilogue: reduce 8 slabs (2 units x 4 c-groups) + 32 rps slices ----
    float* vacc = &Vs[0][0][0][0];              // vacc[8][32][36] overlay (fits)
    float* rsum = &Ps[0][0][0];                 // rsum[32][32] overlay
    {
        const int s = u * 4 + cg;
        float* base = vacc + (s * 32 + 2 * rp) * 36 + dg * 8;
        *(float4*)&base[0]  = acc0a; *(float4*)&base[4]  = acc0b;
        *(float4*)&base[36] = acc1a; *(float4*)&base[40] = acc1b;
        const int qg = utid >> 4;               // 0..15
        rsum[(u * 16 + qg) * 32 + qrt]     = rps0;
        rsum[(u * 16 + qg) * 32 + qrt + 1] = rps1;
    }
    __syncthreads();

    if (tid < 32) {
        float pt = 0.f;
        #pragma unroll
        for (int s2 = 0; s2 < 32; ++s2) pt += rsum[s2 * 32 + tid];
        invL[tid] = 1.0f / pt;
    }
    __syncthreads();

    float* ctxn = &Ks[0][0][0][0];              // ctxn[32][36] overlay
    if (tid < 256) {
        const int r = tid & 31, dq = tid >> 5;  // 8 dim-quads
        float4 sum = make_float4(0.f, 0.f, 0.f, 0.f);
        #pragma unroll
        for (int s = 0; s < 8; ++s) {
            float4 v = *(const float4*)&vacc[(s * 32 + r) * 36 + dq * 4];
            sum.x += v.x; sum.y += v.y; sum.z += v.z; sum.w += v.w;
        }
        const float il = invL[r];
        sum.x *= il; sum.y *= il; sum.z *= il; sum.w *= il;
        *(float4*)&ctxn[r * 36 + dq * 4] = sum;
    }
    __syncthreads();

    // ---- per-head outproj partial, atomically accumulated into out ----
    {
        const int jc = tid & 255, rg = tid >> 8;
        float wo[32];
        #pragma unroll
        for (int k = 0; k < 32; ++k)
            wo[k] = Wo[(h * DHD + k) * DMODEL + jc];
        for (int rr = rg * 16; rr < rg * 16 + 16; ++rr) {
            float a = 0.f;
            #pragma unroll
            for (int k4 = 0; k4 < 8; ++k4) {
                float4 cv = *(const float4*)&ctxn[rr * 36 + k4 * 4];
                a = fmaf(cv.x, wo[k4 * 4 + 0], a);
                a = fmaf(cv.y, wo[k4 * 4 + 1], a);
                a = fmaf(cv.z, wo[k4 * 4 + 2], a);
                a = fmaf(cv.w, wo[k4 * 4 + 3], a);
            }
            atomicAdd(&out[(s0 + rr) * DMODEL + jc], a);
        }
    }
}

extern "C" void kernel_launch(void* const* d_in, const int* in_sizes, int n_in,
                              void* d_out, int out_size, void* d_ws, size_t ws_size,
                              hipStream_t stream)
{
    const float* query  = (const float*)d_in[0];
    const float* value  = (const float*)d_in[1];
    const float* key_in = (const float*)d_in[2];
    const float* Wq = (const float*)d_in[3];
    const float* bq = (const float*)d_in[4];
    const float* Wk = (const float*)d_in[5];
    const float* bk = (const float*)d_in[6];
    const float* Wv = (const float*)d_in[7];
    const float* bv = (const float*)d_in[8];
    const float* Wo = (const float*)d_in[9];
    const float* bo = (const float*)d_in[10];
    const int*   aidx = (const int*)d_in[11];
    const float* mask = (const float*)d_in[12];

    const int M = in_sizes[11] / SQ;   // 768

    float* out        = (float*)d_out;
    float* scores_out = out + SQ * DMODEL;
    float* idx_out    = scores_out + NH * SQ * M;

    float* ws  = (float*)d_ws;
    float* qhp = ws;
    float* khp = qhp + NH * SQ * DHD;
    float* vhp = khp + NH * SQ * DHD;

    proj3<<<dim3(96, 3), 256, 0, stream>>>(
        query, value, key_in, Wq, bq, Wk, bk, Wv, bv,
        bo, out, aidx, idx_out, qhp, khp, vhp);

    attn2<<<dim3(NB, 2, NH), 512, 0, stream>>>(
        qhp, khp, vhp, aidx, mask, Wo, scores_out, out, M);
}